// Round 6
// baseline (491.020 us; speedup 1.0000x reference)
//
#include <hip/hip_runtime.h>
#include <cfloat>
#include <cmath>

#define B_    4
#define SNIP  8
#define CCH   256
#define HW    784
#define THW   6272      // SNIP*HW
#define NROWS 25088     // B_*THW
#define TOPK  5
#define NTILE 49        // 6272/128
#define NPAIR 1225      // 49*50/2

typedef _Float16 f16;
typedef f16   half8 __attribute__((ext_vector_type(8)));
typedef f16   half4 __attribute__((ext_vector_type(4)));
typedef float f32x4 __attribute__((ext_vector_type(4)));

// ---------------------------------------------------------------- utilities
// Branchless sorted-5 insert: 5 v_cmp + cndmask chain, no divergence.
__device__ __forceinline__ void ins5(float key, int idx, float tv[TOPK], int ti[TOPK]) {
    const bool c4 = key > tv[4];
    const bool c3 = key > tv[3];
    const bool c2 = key > tv[2];
    const bool c1 = key > tv[1];
    const bool c0 = key > tv[0];
    tv[4] = c3 ? tv[3] : (c4 ? key : tv[4]);
    ti[4] = c3 ? ti[3] : (c4 ? idx : ti[4]);
    tv[3] = c2 ? tv[2] : (c3 ? key : tv[3]);
    ti[3] = c2 ? ti[2] : (c3 ? idx : ti[3]);
    tv[2] = c1 ? tv[1] : (c2 ? key : tv[2]);
    ti[2] = c1 ? ti[1] : (c2 ? idx : ti[2]);
    tv[1] = c0 ? tv[0] : (c1 ? key : tv[1]);
    ti[1] = c0 ? ti[0] : (c1 ? idx : ti[1]);
    tv[0] = c0 ? key  : tv[0];
    ti[0] = c0 ? idx  : ti[0];
}

__device__ __forceinline__ void async16(const void* g, void* l) {
    __builtin_amdgcn_global_load_lds(
        (const __attribute__((address_space(1))) void*)g,
        (__attribute__((address_space(3))) void*)l, 16, 0, 0);
}

// rotated transpose layout: [128][64] f32, addr = row*64 + ((col+row)&63).
// bank = (row+col)%32 — identical conflict profile to the old stride-65
// (65 == 1 mod 32), but exactly 32KB -> 5 blocks/CU instead of 4.
__device__ __forceinline__ int tta(int row, int col) {
    return (row << 6) | ((col + row) & 63);
}

// templated epilogues: FM=false drops the same-frame select entirely
// (wave-uniform dispatch; ~86% of tile pairs share no frame).
template<bool FM>
__device__ __forceinline__ void epi_norm(const f32x4 (&acc)[4][4], int t0wrq, const int (&loj)[4],
                                         float (&tv)[4][TOPK], int (&ti)[4][TOPK]) {
#pragma unroll
    for (int i = 0; i < 4; ++i) {
#pragma unroll
        for (int reg = 0; reg < 4; ++reg) {
            const int t = t0wrq + 16 * i + reg;
#pragma unroll
            for (int j = 0; j < 4; ++j) {
                float key = acc[i][j][reg];
                if (FM) key = ((unsigned)(t - loj[j]) < (unsigned)HW) ? -FLT_MAX : key;
                ins5(key, t, tv[j], ti[j]);
            }
        }
    }
}

template<bool FM>
__device__ __forceinline__ void epi_tr(const float* TT, int wrb, int q, int wc, int lm,
                                       int j0h, const int (&lo2)[4],
                                       float (&tv2)[4][TOPK], int (&ti2)[4][TOPK]) {
#pragma unroll
    for (int ii = 0; ii < 2; ++ii) {
        const int spb = wrb * 32 + 16 * ii + 4 * q;
        const int sg0 = j0h + spb;
#pragma unroll
        for (int reg = 0; reg < 4; ++reg) {
            const int sg = sg0 + reg;
#pragma unroll
            for (int j = 0; j < 4; ++j) {
                float key = TT[tta(wc + 16 * j + lm, spb + reg)];
                if (FM) key = ((unsigned)(sg - lo2[j]) < (unsigned)HW) ? -FLT_MAX : key;
                ins5(key, sg, tv2[j], ti2[j]);
            }
        }
    }
}

// ------------------------------------------------- 1. fused transpose + rownorm + NORMALIZED f16 split
__global__ __launch_bounds__(256)
void transpose_norm_split_kernel(const float* __restrict__ x, f16* __restrict__ Xs,
                                 float* __restrict__ nrm) {
    __shared__ float T[256][33];
    const int bs = blockIdx.x;
    const int p0 = blockIdx.y * 32;
    const int b = bs >> 3, f = bs & 7;
    const int tid = threadIdx.x;

    const int pl = tid & 31, ch = tid >> 5;
    const int p = p0 + pl;
    if (p < HW) {
#pragma unroll
        for (int cc = 0; cc < 32; ++cc) {
            const int c = cc * 8 + ch;
            T[c][pl] = x[((size_t)bs * CCH + c) * HW + p];
        }
    }
    __syncthreads();

    const int rloc = tid >> 3, k = tid & 7;
    const int gp = p0 + rloc;
    const size_t trow = (size_t)b * THW + (size_t)f * HW + gp;

    float s = 0.0f;
    if (gp < HW) {
#pragma unroll
        for (int j = 0; j < 32; ++j) {
            const float v = T[k * 32 + j][rloc];
            s += v * v;
        }
    }
    s += __shfl_xor(s, 1, 64);
    s += __shfl_xor(s, 2, 64);
    s += __shfl_xor(s, 4, 64);

    if (gp < HW) {
        const float sq = sqrtf(s);
        const float rs = 1.0f / sq;
        if (k == 0) nrm[trow] = sq;
#pragma unroll
        for (int q = 0; q < 4; ++q) {
            half8 hv, lv;
#pragma unroll
            for (int j = 0; j < 8; ++j) {
                const float v = T[k * 32 + q * 8 + j][rloc] * rs;
                const f16 h = (f16)v;
                hv[j] = h;
                lv[j] = (f16)(v - (float)h);
            }
            *(half8*)(Xs + trow * 512 + k * 32 + q * 8) = hv;
            *(half8*)(Xs + trow * 512 + 256 + k * 32 + q * 8) = lv;
        }
    }
}

// ------------------------------------------------- 2a. block-level top5 merge + SoA partial store
__device__ __forceinline__ void block_merge_store(
    const float (*tv)[TOPK], const int (*ti)[TOPK], char* smem,
    int tid, int wid, int q, int wc, int lm,
    int rslot, size_t gcol0,
    float* __restrict__ pval, unsigned short* __restrict__ pidx) {
    float* Mv = (float*)smem;                              // [40][132] f32 = 21120 B
    unsigned short* Mi = (unsigned short*)(smem + 21120);  // [40][132] u16 = 10560 B
    const int slot = (wid >> 1) * 4 + q;
    __syncthreads();                                       // previous smem use done
#pragma unroll
    for (int j = 0; j < 4; ++j) {
        const int c128 = wc + 16 * j + lm;
#pragma unroll
        for (int s = 0; s < TOPK; ++s) {
            Mv[(slot * TOPK + s) * 132 + c128] = tv[j][s];
            Mi[(slot * TOPK + s) * 132 + c128] = (unsigned short)ti[j][s];
        }
    }
    __syncthreads();
    if (tid < 128) {
        float bv5[TOPK]; int bi5[TOPK];
#pragma unroll
        for (int s = 0; s < TOPK; ++s) { bv5[s] = -FLT_MAX; bi5[s] = 0; }
        for (int s = 0; s < 40; ++s) ins5(Mv[s * 132 + tid], (int)Mi[s * 132 + tid], bv5, bi5);
#pragma unroll
        for (int s = 0; s < TOPK; ++s) {
            const size_t o = ((size_t)(rslot * TOPK + s)) * NROWS + gcol0 + tid;
            pval[o] = bv5[s];
            pidx[o] = (unsigned short)bi5[s];
        }
    }
}

// ------------------------------------------------- 2b. SYMMETRIC gram MFMA + dual top-5
// r5 structure; LDS trimmed to exactly 32KB (rotation TT) -> 5 blocks/CU;
// wave-uniform frame-mask skip for the ~86% of tile pairs with no shared frame.
__global__ __launch_bounds__(256, 4)
void gram_sym_kernel(const f16* __restrict__ Xs,
                     float* __restrict__ pval, unsigned short* __restrict__ pidx) {
    __shared__ __align__(16) char smem[32768];   // staging 32KB | TT rot [128][64] f32 | merge 31.7KB
    f16* As = (f16*)smem;                 // [128][64] halves, unit-swizzled
    f16* Bs = As + 8192;
    float* TT = (float*)smem;             // rotated transpose buffer (reused post-loop)

    const int tid = threadIdx.x;
    const int lane = tid & 63, wid = tid >> 6;
    const int wr = (wid >> 1) * 64, wc = (wid & 1) * 64;
    const int lm = lane & 15, q = lane >> 4;
    const int lm7 = lm & 7;
    const int b = blockIdx.z;

    // decode pair p -> (ri <= cj), p = cj*(cj+1)/2 + ri
    const int p = blockIdx.x;
    int cj = (int)((sqrtf(8.0f * (float)p + 1.0f) - 1.0f) * 0.5f);
    while ((cj + 1) * (cj + 2) / 2 <= p) ++cj;
    while (cj * (cj + 1) / 2 > p) --cj;
    const int ri = p - cj * (cj + 1) / 2;
    const int t0 = ri * 128, j0 = cj * 128;

    // do the two tiles touch a common 784-frame? (wave-uniform)
    const int ftl = t0 / HW, fth = (t0 + 127) / HW;
    const int fjl = j0 / HW, fjh = (j0 + 127) / HW;
    const bool fmask = (ftl <= fjh) && (fjl <= fth);

    const size_t bbase = (size_t)b * THW;
    const f16* Xb = Xs + bbase * 512;

    const int srow = tid >> 3;
    const int skk = (((tid & 7) ^ (srow & 7)) * 8);

    // frame base of each of this thread's 4 output columns (normal side)
    int loj[4];
#pragma unroll
    for (int j = 0; j < 4; ++j) loj[j] = ((j0 + wc + 16 * j + lm) / HW) * HW;

    float tv[4][TOPK];
    int   ti[4][TOPK];
#pragma unroll
    for (int j = 0; j < 4; ++j)
#pragma unroll
        for (int s = 0; s < TOPK; ++s) { tv[j][s] = -FLT_MAX; ti[j][s] = 0; }

    const int segA[3] = {0, 256, 0};
    const int segB[3] = {0, 0, 256};

    f32x4 acc[4][4];
#pragma unroll
    for (int i = 0; i < 4; ++i)
#pragma unroll
        for (int j = 0; j < 4; ++j) acc[i][j] = (f32x4)0.0f;

    for (int cc = 0; cc < 12; ++cc) {
        const int seg = cc >> 2, k64 = (cc & 3) * 64;
        const int aoff = segA[seg] + k64 + skk;
        const int boff = segB[seg] + k64 + skk;
#pragma unroll
        for (int pp = 0; pp < 4; ++pp)
            async16(Xb + (size_t)(t0 + srow + 32 * pp) * 512 + aoff,
                    smem + wid * 1024 + pp * 4096);
#pragma unroll
        for (int pp = 0; pp < 4; ++pp)
            async16(Xb + (size_t)(j0 + srow + 32 * pp) * 512 + boff,
                    smem + 16384 + wid * 1024 + pp * 4096);
        __syncthreads();
#pragma unroll
        for (int ks = 0; ks < 2; ++ks) {
            const int ku = (((4 * ks + q) ^ lm7) * 8);
            half8 av[4], bv[4];
#pragma unroll
            for (int i = 0; i < 4; ++i)
                av[i] = *(const half8*)(As + (wr + 16 * i + lm) * 64 + ku);
#pragma unroll
            for (int j = 0; j < 4; ++j)
                bv[j] = *(const half8*)(Bs + (wc + 16 * j + lm) * 64 + ku);
#pragma unroll
            for (int i = 0; i < 4; ++i)
#pragma unroll
                for (int j = 0; j < 4; ++j)
                    acc[i][j] = __builtin_amdgcn_mfma_f32_16x16x32_f16(av[i], bv[j], acc[i][j], 0, 0, 0);
        }
        __syncthreads();
    }

    // ---- normal side: columns in cj-tile, candidates t in ri-tile
    const int t0wrq = t0 + wr + 4 * q;
    if (fmask) epi_norm<true >(acc, t0wrq, loj, tv, ti);
    else       epi_norm<false>(acc, t0wrq, loj, tv, ti);
    block_merge_store(tv, ti, smem, tid, wid, q, wc, lm,
                      ri, bbase + (size_t)j0, pval, pidx);

    // ---- transposed side: columns in ri-tile, candidates s in cj-tile
    if (ri != cj) {
        int lo2[4];
#pragma unroll
        for (int j = 0; j < 4; ++j) lo2[j] = ((t0 + wc + 16 * j + lm) / HW) * HW;
        float tv2[4][TOPK];
        int   ti2[4][TOPK];
#pragma unroll
        for (int j = 0; j < 4; ++j)
#pragma unroll
            for (int s = 0; s < TOPK; ++s) { tv2[j][s] = -FLT_MAX; ti2[j][s] = 0; }
        const int wrb = wid >> 1;
#pragma unroll
        for (int h = 0; h < 2; ++h) {
            __syncthreads();             // previous smem readers done
            if ((wid & 1) == h) {        // waves holding s-half h write their acc
#pragma unroll
                for (int i = 0; i < 4; ++i)
#pragma unroll
                    for (int j = 0; j < 4; ++j)
#pragma unroll
                        for (int reg = 0; reg < 4; ++reg)
                            TT[tta(wr + 16 * i + 4 * q + reg, 16 * j + lm)] = acc[i][j][reg];
            }
            __syncthreads();
            if (fmask) epi_tr<true >(TT, wrb, q, wc, lm, j0 + 64 * h, lo2, tv2, ti2);
            else       epi_tr<false>(TT, wrb, q, wc, lm, j0 + 64 * h, lo2, tv2, ti2);
        }
        block_merge_store(tv2, ti2, smem, tid, wid, q, wc, lm,
                          cj, bbase + (size_t)t0, pval, pidx);
    }
}

// ------------------------------------------------- 3. merge 49 tile-partials per column
__global__ __launch_bounds__(256)
void merge_topk_sym_kernel(const float* __restrict__ pval, const unsigned short* __restrict__ pidx,
                           int* __restrict__ idx5) {
    __shared__ float Lv[4][TOPK][64];
    __shared__ unsigned short Li[4][TOPK][64];
    const int tid = threadIdx.x;
    const int part = tid >> 6, cl = tid & 63;
    const int col = blockIdx.x * 64 + cl;

    float bv5[TOPK]; int bi5[TOPK];
#pragma unroll
    for (int s = 0; s < TOPK; ++s) { bv5[s] = -FLT_MAX; bi5[s] = 0; }

    const int r0 = part * 13;
    const int r1 = (r0 + 13 < NTILE) ? r0 + 13 : NTILE;
    for (int r = r0; r < r1; ++r) {
#pragma unroll
        for (int s = 0; s < TOPK; ++s) {
            const size_t o = ((size_t)(r * TOPK + s)) * NROWS + col;
            ins5(pval[o], (int)pidx[o], bv5, bi5);
        }
    }
#pragma unroll
    for (int s = 0; s < TOPK; ++s) { Lv[part][s][cl] = bv5[s]; Li[part][s][cl] = (unsigned short)bi5[s]; }
    __syncthreads();
    if (tid < 64) {
        float cv[TOPK]; int ci[TOPK];
#pragma unroll
        for (int s = 0; s < TOPK; ++s) { cv[s] = -FLT_MAX; ci[s] = 0; }
#pragma unroll
        for (int pp = 0; pp < 4; ++pp)
#pragma unroll
            for (int s = 0; s < TOPK; ++s) ins5(Lv[pp][s][tid], (int)Li[pp][s][tid], cv, ci);
        int* op = idx5 + (size_t)col * TOPK;
#pragma unroll
        for (int s = 0; s < TOPK; ++s) op[s] = ci[s];
    }
}

// ------------------------------------------------- 4. gather (normalized f16 pair * nrm) + max + BN partials
__global__ __launch_bounds__(256)
void gather_bn_kernel(const f16* __restrict__ Xs, const float* __restrict__ nrm,
                      const int* __restrict__ idx5,
                      f16* __restrict__ yf, float* __restrict__ partial) {
    __shared__ float ls[2][4][256];
    const int tid = threadIdx.x;
    const int wid = tid >> 6, lane = tid & 63;
    const int row0 = blockIdx.x * 32 + wid * 8;
    float s1x = 0, s1y = 0, s1z = 0, s1w = 0;
    float s2x = 0, s2y = 0, s2z = 0, s2w = 0;
    for (int rr = 0; rr < 8; ++rr) {
        const int row = row0 + rr;
        const int b = row / THW;
        const int* id = idx5 + (size_t)row * TOPK;
        const f16* base = Xs + (size_t)b * THW * 512;
        const float* nb = nrm + (size_t)b * THW;
        float4 m = make_float4(-FLT_MAX, -FLT_MAX, -FLT_MAX, -FLT_MAX);
#pragma unroll
        for (int i = 0; i < TOPK; ++i) {
            const int t = id[i];
            const float nv = nb[t];
            const f16* rp = base + (size_t)t * 512 + lane * 4;
            const half4 h = *(const half4*)rp;
            const half4 l = *(const half4*)(rp + 256);
            m.x = fmaxf(m.x, ((float)h.x + (float)l.x) * nv);
            m.y = fmaxf(m.y, ((float)h.y + (float)l.y) * nv);
            m.z = fmaxf(m.z, ((float)h.z + (float)l.z) * nv);
            m.w = fmaxf(m.w, ((float)h.w + (float)l.w) * nv);
        }
        half4 ym; ym.x = (f16)m.x; ym.y = (f16)m.y; ym.z = (f16)m.z; ym.w = (f16)m.w;
        *(half4*)(yf + (size_t)row * CCH + lane * 4) = ym;
        s1x += m.x; s1y += m.y; s1z += m.z; s1w += m.w;
        s2x += m.x * m.x; s2y += m.y * m.y; s2z += m.z * m.z; s2w += m.w * m.w;
    }
    *(float4*)&ls[0][wid][lane * 4] = make_float4(s1x, s1y, s1z, s1w);
    *(float4*)&ls[1][wid][lane * 4] = make_float4(s2x, s2y, s2z, s2w);
    __syncthreads();
    const float a  = ls[0][0][tid] + ls[0][1][tid] + ls[0][2][tid] + ls[0][3][tid];
    const float b2 = ls[1][0][tid] + ls[1][1][tid] + ls[1][2][tid] + ls[1][3][tid];
    partial[(size_t)blockIdx.x * 512 + tid] = a;
    partial[(size_t)blockIdx.x * 512 + 256 + tid] = b2;
}

// ------------------------------------------------- 5. BN finalize -> scale/shift
__global__ __launch_bounds__(256)
void bn_final_kernel(const float* __restrict__ partial, const float* __restrict__ gamma,
                     const float* __restrict__ beta, float* __restrict__ ab) {
    const int c = blockIdx.x;
    const int tid = threadIdx.x;
    float s1 = 0, s2 = 0;
    for (int p = tid; p < 784; p += 256) {
        s1 += partial[(size_t)p * 512 + c];
        s2 += partial[(size_t)p * 512 + 256 + c];
    }
    __shared__ float r1[256], r2[256];
    r1[tid] = s1; r2[tid] = s2;
    __syncthreads();
    for (int off = 128; off > 0; off >>= 1) {
        if (tid < off) { r1[tid] += r1[tid + off]; r2[tid] += r2[tid + off]; }
        __syncthreads();
    }
    if (tid == 0) {
        const float inv_n = 1.0f / 25088.0f;
        const float mean = r1[0] * inv_n;
        const float var  = r2[0] * inv_n - mean * mean;
        const float a = gamma[c] / sqrtf(var + 1e-5f);
        ab[c] = a;
        ab[256 + c] = beta[c] - mean * a;
    }
}

// ------------------------------------------------- 6. relu(BN) -> 1x1 conv (f16 MFMA) + identity
__global__ __launch_bounds__(256, 2)
void conv_f16_kernel(const f16* __restrict__ yf, const float* __restrict__ w,
                     const float* __restrict__ ab, const float* __restrict__ cb,
                     const float* __restrict__ x, float* __restrict__ out) {
    __shared__ __align__(16) f16 smem[2 * 128 * 64];
    f16* As = smem;
    f16* Ws = smem + 8192;

    const int tid = threadIdx.x;
    const int lane = tid & 63, wid = tid >> 6;
    const int wr = (wid >> 1) * 64, wc = (wid & 1) * 64;
    const int lm = lane & 15, q = lane >> 4;
    const int lm7 = lm & 7;
    const int R0 = blockIdx.x * 128;
    const int o0 = blockIdx.y * 128;
    const int g8 = (tid & 7) * 8;
    const int sr = tid >> 3;

    f32x4 acc[4][4];
#pragma unroll
    for (int i = 0; i < 4; ++i)
#pragma unroll
        for (int j = 0; j < 4; ++j) acc[i][j] = (f32x4)0.0f;

    float cbv[4];
#pragma unroll
    for (int j = 0; j < 4; ++j) cbv[j] = cb[o0 + wc + 16 * j + lm];

    for (int kc = 0; kc < CCH; kc += 64) {
        const int cbase = kc + g8;
        const float4 sa0 = *(const float4*)(ab + cbase);
        const float4 sa1 = *(const float4*)(ab + cbase + 4);
        const float4 sb0 = *(const float4*)(ab + 256 + cbase);
        const float4 sb1 = *(const float4*)(ab + 256 + cbase + 4);
#pragma unroll
        for (int p = 0; p < 4; ++p) {
            const int r = sr + 32 * p;
            const half8 hv = *(const half8*)(yf + (size_t)(R0 + r) * CCH + cbase);
            half8 z;
            z[0] = (f16)fmaxf(fmaf((float)hv[0], sa0.x, sb0.x), 0.0f);
            z[1] = (f16)fmaxf(fmaf((float)hv[1], sa0.y, sb0.y), 0.0f);
            z[2] = (f16)fmaxf(fmaf((float)hv[2], sa0.z, sb0.z), 0.0f);
            z[3] = (f16)fmaxf(fmaf((float)hv[3], sa0.w, sb0.w), 0.0f);
            z[4] = (f16)fmaxf(fmaf((float)hv[4], sa1.x, sb1.x), 0.0f);
            z[5] = (f16)fmaxf(fmaf((float)hv[5], sa1.y, sb1.y), 0.0f);
            z[6] = (f16)fmaxf(fmaf((float)hv[6], sa1.z, sb1.z), 0.0f);
            z[7] = (f16)fmaxf(fmaf((float)hv[7], sa1.w, sb1.w), 0.0f);
            *(half8*)(As + r * 64 + (((tid & 7) ^ (r & 7)) * 8)) = z;
        }
#pragma unroll
        for (int p = 0; p < 4; ++p) {
            const int ol = sr + 32 * p;
            const float4 w0 = *(const float4*)(w + (size_t)(o0 + ol) * CCH + cbase);
            const float4 w1 = *(const float4*)(w + (size_t)(o0 + ol) * CCH + cbase + 4);
            half8 z;
            z[0] = (f16)w0.x; z[1] = (f16)w0.y; z[2] = (f16)w0.z; z[3] = (f16)w0.w;
            z[4] = (f16)w1.x; z[5] = (f16)w1.y; z[6] = (f16)w1.z; z[7] = (f16)w1.w;
            *(half8*)(Ws + ol * 64 + (((tid & 7) ^ (ol & 7)) * 8)) = z;
        }
        __syncthreads();
#pragma unroll
        for (int ks = 0; ks < 2; ++ks) {
            const int ku = (((4 * ks + q) ^ lm7) * 8);
            half8 av[4], bv[4];
#pragma unroll
            for (int i = 0; i < 4; ++i)
                av[i] = *(const half8*)(As + (wr + 16 * i + lm) * 64 + ku);
#pragma unroll
            for (int j = 0; j < 4; ++j)
                bv[j] = *(const half8*)(Ws + (wc + 16 * j + lm) * 64 + ku);
#pragma unroll
            for (int i = 0; i < 4; ++i)
#pragma unroll
                for (int j = 0; j < 4; ++j)
                    acc[i][j] = __builtin_amdgcn_mfma_f32_16x16x32_f16(av[i], bv[j], acc[i][j], 0, 0, 0);
        }
        __syncthreads();
    }
#pragma unroll
    for (int i = 0; i < 4; ++i) {
#pragma unroll
        for (int reg = 0; reg < 4; ++reg) {
            const int R = R0 + wr + 16 * i + 4 * q + reg;
            const int bs = R / HW;
            const int hw = R - bs * HW;
#pragma unroll
            for (int j = 0; j < 4; ++j) {
                const int o = o0 + wc + 16 * j + lm;
                const size_t oi = ((size_t)bs * CCH + o) * HW + hw;
                out[oi] = acc[i][j][reg] + cbv[j] + x[oi];
            }
        }
    }
}

// ------------------------------------------------- launch
extern "C" void kernel_launch(void* const* d_in, const int* in_sizes, int n_in,
                              void* d_out, int out_size, void* d_ws, size_t ws_size,
                              hipStream_t stream) {
    const float* x      = (const float*)d_in[0];
    const float* gamma  = (const float*)d_in[1];
    const float* beta   = (const float*)d_in[2];
    const float* conv_w = (const float*)d_in[3];
    const float* conv_b = (const float*)d_in[4];
    float* out = (float*)d_out;

    float* ws = (float*)d_ws;
    f16*   Xsp  = (f16*)ws;                            // [25088][512] halves = 6,422,528 f
    f16*   yf   = (f16*)(ws + 6422528);                // [25088][256] halves = 3,211,264 f
    float* nrm  = ws + 9633792;                        // 25,088
    float* part = ws + 9658880;                        // 401,408
    float* ab   = ws + 10060288;                       // 512
    int*   idx5 = (int*)(ws + 10060800);               // 125,440 ints
    float* pvalS = ws + 10186240;                              // [49][5][25088] f32 SoA
    unsigned short* pidxS = (unsigned short*)(ws + 16332800);  // [49][5][25088] u16 SoA
    // total = 19,406,080 floats = 77.6 MB

    transpose_norm_split_kernel<<<dim3(32, 25), 256, 0, stream>>>(x, Xsp, nrm);
    gram_sym_kernel<<<dim3(NPAIR, 1, B_), 256, 0, stream>>>(Xsp, pvalS, pidxS);
    merge_topk_sym_kernel<<<NROWS / 64, 256, 0, stream>>>(pvalS, pidxS, idx5);
    gather_bn_kernel<<<NROWS / 32, 256, 0, stream>>>(Xsp, nrm, idx5, yf, part);
    bn_final_kernel<<<256, 256, 0, stream>>>(part, gamma, beta, ab);
    conv_f16_kernel<<<dim3(NROWS / 128, 2), 256, 0, stream>>>(yf, conv_w, ab, conv_b, x, out);
}

// Round 7
// 402.150 us; speedup vs baseline: 1.2210x; 1.2210x over previous
//
#include <hip/hip_runtime.h>
#include <cfloat>
#include <cmath>

#define B_    4
#define SNIP  8
#define CCH   256
#define HW    784
#define THW   6272      // SNIP*HW
#define NROWS 25088     // B_*THW
#define TOPK  5
#define NTILE 49        // 6272/128
#define NPAIR 1225      // 49*50/2

typedef _Float16 f16;
typedef f16   half8 __attribute__((ext_vector_type(8)));
typedef f16   half4 __attribute__((ext_vector_type(4)));
typedef float f32x4 __attribute__((ext_vector_type(4)));

// ---------------------------------------------------------------- utilities
// Branchless sorted-5 insert: 5 v_cmp + cndmask chain, no divergence.
// Strict '>' so ties keep the earlier-inserted entry.
__device__ __forceinline__ void ins5(float key, int idx, float tv[TOPK], int ti[TOPK]) {
    const bool c4 = key > tv[4];
    const bool c3 = key > tv[3];
    const bool c2 = key > tv[2];
    const bool c1 = key > tv[1];
    const bool c0 = key > tv[0];
    tv[4] = c3 ? tv[3] : (c4 ? key : tv[4]);
    ti[4] = c3 ? ti[3] : (c4 ? idx : ti[4]);
    tv[3] = c2 ? tv[2] : (c3 ? key : tv[3]);
    ti[3] = c2 ? ti[2] : (c3 ? idx : ti[3]);
    tv[2] = c1 ? tv[1] : (c2 ? key : tv[2]);
    ti[2] = c1 ? ti[1] : (c2 ? idx : ti[2]);
    tv[1] = c0 ? tv[0] : (c1 ? key : tv[1]);
    ti[1] = c0 ? ti[0] : (c1 ? idx : ti[1]);
    tv[0] = c0 ? key  : tv[0];
    ti[0] = c0 ? idx  : ti[0];
}

__device__ __forceinline__ void async16(const void* g, void* l) {
    __builtin_amdgcn_global_load_lds(
        (const __attribute__((address_space(1))) void*)g,
        (__attribute__((address_space(3))) void*)l, 16, 0, 0);
}

// ------------------------------------------------- 1. fused transpose + rownorm + NORMALIZED f16 split
__global__ __launch_bounds__(256)
void transpose_norm_split_kernel(const float* __restrict__ x, f16* __restrict__ Xs,
                                 float* __restrict__ nrm) {
    __shared__ float T[256][33];
    const int bs = blockIdx.x;
    const int p0 = blockIdx.y * 32;
    const int b = bs >> 3, f = bs & 7;
    const int tid = threadIdx.x;

    const int pl = tid & 31, ch = tid >> 5;
    const int p = p0 + pl;
    if (p < HW) {
#pragma unroll
        for (int cc = 0; cc < 32; ++cc) {
            const int c = cc * 8 + ch;
            T[c][pl] = x[((size_t)bs * CCH + c) * HW + p];
        }
    }
    __syncthreads();

    const int rloc = tid >> 3, k = tid & 7;
    const int gp = p0 + rloc;
    const size_t trow = (size_t)b * THW + (size_t)f * HW + gp;

    float s = 0.0f;
    if (gp < HW) {
#pragma unroll
        for (int j = 0; j < 32; ++j) {
            const float v = T[k * 32 + j][rloc];
            s += v * v;
        }
    }
    s += __shfl_xor(s, 1, 64);
    s += __shfl_xor(s, 2, 64);
    s += __shfl_xor(s, 4, 64);

    if (gp < HW) {
        const float sq = sqrtf(s);
        const float rs = 1.0f / sq;
        if (k == 0) nrm[trow] = sq;
#pragma unroll
        for (int q = 0; q < 4; ++q) {
            half8 hv, lv;
#pragma unroll
            for (int j = 0; j < 8; ++j) {
                const float v = T[k * 32 + q * 8 + j][rloc] * rs;
                const f16 h = (f16)v;
                hv[j] = h;
                lv[j] = (f16)(v - (float)h);
            }
            *(half8*)(Xs + trow * 512 + k * 32 + q * 8) = hv;
            *(half8*)(Xs + trow * 512 + 256 + k * 32 + q * 8) = lv;
        }
    }
}

// ------------------------------------------------- 2a. block-level top5 merge + SoA partial store
__device__ __forceinline__ void block_merge_store(
    const float (*tv)[TOPK], const int (*ti)[TOPK], char* smem,
    int tid, int wid, int q, int wc, int lm,
    int rslot, size_t gcol0,
    float* __restrict__ pval, unsigned short* __restrict__ pidx) {
    float* Mv = (float*)smem;                              // [40][132] f32 = 21120 B
    unsigned short* Mi = (unsigned short*)(smem + 21120);  // [40][132] u16 = 10560 B
    const int slot = (wid >> 1) * 4 + q;
    __syncthreads();                                       // previous smem use done
#pragma unroll
    for (int j = 0; j < 4; ++j) {
        const int c128 = wc + 16 * j + lm;
#pragma unroll
        for (int s = 0; s < TOPK; ++s) {
            Mv[(slot * TOPK + s) * 132 + c128] = tv[j][s];
            Mi[(slot * TOPK + s) * 132 + c128] = (unsigned short)ti[j][s];
        }
    }
    __syncthreads();
    if (tid < 128) {
        float bv5[TOPK]; int bi5[TOPK];
#pragma unroll
        for (int s = 0; s < TOPK; ++s) { bv5[s] = -FLT_MAX; bi5[s] = 0; }
        for (int s = 0; s < 40; ++s) ins5(Mv[s * 132 + tid], (int)Mi[s * 132 + tid], bv5, bi5);
#pragma unroll
        for (int s = 0; s < TOPK; ++s) {
            const size_t o = ((size_t)(rslot * TOPK + s)) * NROWS + gcol0 + tid;
            pval[o] = bv5[s];
            pidx[o] = (unsigned short)bi5[s];
        }
    }
}

// ------------------------------------------------- 2b. SYMMETRIC gram MFMA + dual top-5
// r5 structure exactly (33280 LDS, no swizzle, 2-barrier K-loop); epilogue
// uses range-test frame masks folded into the key + branchless ins5.
__global__ __launch_bounds__(256, 3)
void gram_sym_kernel(const f16* __restrict__ Xs,
                     float* __restrict__ pval, unsigned short* __restrict__ pidx) {
    __shared__ __align__(16) char smem[33280];   // staging 32KB | TT [128][65] f32 | merge 31.7KB
    f16* As = (f16*)smem;                 // [128][64] halves, unit-swizzled
    f16* Bs = As + 8192;
    float* TT = (float*)smem;             // [128][65] transpose buffer (reused post-loop)

    const int tid = threadIdx.x;
    const int lane = tid & 63, wid = tid >> 6;
    const int wr = (wid >> 1) * 64, wc = (wid & 1) * 64;
    const int lm = lane & 15, q = lane >> 4;
    const int lm7 = lm & 7;
    const int b = blockIdx.z;

    // decode pair p -> (ri <= cj), p = cj*(cj+1)/2 + ri
    const int p = blockIdx.x;
    int cj = (int)((sqrtf(8.0f * (float)p + 1.0f) - 1.0f) * 0.5f);
    while ((cj + 1) * (cj + 2) / 2 <= p) ++cj;
    while (cj * (cj + 1) / 2 > p) --cj;
    const int ri = p - cj * (cj + 1) / 2;
    const int t0 = ri * 128, j0 = cj * 128;

    const size_t bbase = (size_t)b * THW;
    const f16* Xb = Xs + bbase * 512;

    const int srow = tid >> 3;
    const int skk = (((tid & 7) ^ (srow & 7)) * 8);

    // frame base of each of this thread's 4 output columns (normal side)
    int loj[4];
#pragma unroll
    for (int j = 0; j < 4; ++j) loj[j] = ((j0 + wc + 16 * j + lm) / HW) * HW;

    float tv[4][TOPK];
    int   ti[4][TOPK];
#pragma unroll
    for (int j = 0; j < 4; ++j)
#pragma unroll
        for (int s = 0; s < TOPK; ++s) { tv[j][s] = -FLT_MAX; ti[j][s] = 0; }

    const int segA[3] = {0, 256, 0};
    const int segB[3] = {0, 0, 256};

    f32x4 acc[4][4];
#pragma unroll
    for (int i = 0; i < 4; ++i)
#pragma unroll
        for (int j = 0; j < 4; ++j) acc[i][j] = (f32x4)0.0f;

    for (int cc = 0; cc < 12; ++cc) {
        const int seg = cc >> 2, k64 = (cc & 3) * 64;
        const int aoff = segA[seg] + k64 + skk;
        const int boff = segB[seg] + k64 + skk;
#pragma unroll
        for (int pp = 0; pp < 4; ++pp)
            async16(Xb + (size_t)(t0 + srow + 32 * pp) * 512 + aoff,
                    smem + wid * 1024 + pp * 4096);
#pragma unroll
        for (int pp = 0; pp < 4; ++pp)
            async16(Xb + (size_t)(j0 + srow + 32 * pp) * 512 + boff,
                    smem + 16384 + wid * 1024 + pp * 4096);
        __syncthreads();
#pragma unroll
        for (int ks = 0; ks < 2; ++ks) {
            const int ku = (((4 * ks + q) ^ lm7) * 8);
            half8 av[4], bv[4];
#pragma unroll
            for (int i = 0; i < 4; ++i)
                av[i] = *(const half8*)(As + (wr + 16 * i + lm) * 64 + ku);
#pragma unroll
            for (int j = 0; j < 4; ++j)
                bv[j] = *(const half8*)(Bs + (wc + 16 * j + lm) * 64 + ku);
#pragma unroll
            for (int i = 0; i < 4; ++i)
#pragma unroll
                for (int j = 0; j < 4; ++j)
                    acc[i][j] = __builtin_amdgcn_mfma_f32_16x16x32_f16(av[i], bv[j], acc[i][j], 0, 0, 0);
        }
        __syncthreads();
    }

    // ---- normal side: columns in cj-tile, candidates t in ri-tile
#pragma unroll
    for (int i = 0; i < 4; ++i) {
        const int tb = t0 + wr + 16 * i + 4 * q;
#pragma unroll
        for (int reg = 0; reg < 4; ++reg) {
            const int t = tb + reg;
#pragma unroll
            for (int j = 0; j < 4; ++j) {
                // same-frame -> key collapses to -FLT_MAX (never displaces)
                const float key = ((unsigned)(t - loj[j]) < (unsigned)HW)
                                  ? -FLT_MAX : acc[i][j][reg];
                ins5(key, t, tv[j], ti[j]);
            }
        }
    }
    block_merge_store(tv, ti, smem, tid, wid, q, wc, lm,
                      ri, bbase + (size_t)j0, pval, pidx);

    // ---- transposed side: columns in ri-tile, candidates s in cj-tile
    if (ri != cj) {
        int lo2[4];
#pragma unroll
        for (int j = 0; j < 4; ++j) lo2[j] = ((t0 + wc + 16 * j + lm) / HW) * HW;
        float tv2[4][TOPK];
        int   ti2[4][TOPK];
#pragma unroll
        for (int j = 0; j < 4; ++j)
#pragma unroll
            for (int s = 0; s < TOPK; ++s) { tv2[j][s] = -FLT_MAX; ti2[j][s] = 0; }
        const int wrb = wid >> 1;
#pragma unroll
        for (int h = 0; h < 2; ++h) {
            __syncthreads();             // previous smem readers done
            if ((wid & 1) == h) {        // waves holding s-half h write their acc
#pragma unroll
                for (int i = 0; i < 4; ++i)
#pragma unroll
                    for (int j = 0; j < 4; ++j)
#pragma unroll
                        for (int reg = 0; reg < 4; ++reg)
                            TT[(wr + 16 * i + 4 * q + reg) * 65 + 16 * j + lm] = acc[i][j][reg];
            }
            __syncthreads();
#pragma unroll
            for (int ii = 0; ii < 2; ++ii) {
                const int spb = wrb * 32 + 16 * ii + 4 * q;    // s-local within half
                const int sg0 = j0 + 64 * h + spb;             // global candidate col
#pragma unroll
                for (int reg = 0; reg < 4; ++reg) {
                    const int sg = sg0 + reg;
#pragma unroll
                    for (int j = 0; j < 4; ++j) {
                        const float raw = TT[(wc + 16 * j + lm) * 65 + spb + reg];
                        const float key = ((unsigned)(sg - lo2[j]) < (unsigned)HW)
                                          ? -FLT_MAX : raw;
                        ins5(key, sg, tv2[j], ti2[j]);
                    }
                }
            }
        }
        block_merge_store(tv2, ti2, smem, tid, wid, q, wc, lm,
                          cj, bbase + (size_t)t0, pval, pidx);
    }
}

// ------------------------------------------------- 3. FUSED merge(49 tile-partials) + gather + max + BN partials
// Block = 32 rows (= 32 partial-columns). Phase 1: 8 parts x 32 cols, each part
// scans its ascending tile range (coalesced SoA loads). Phase 2: per-column
// final merge in ascending part order (tie semantics identical to the old
// two-kernel path). Phase 3: original gather/max/BN using LDS indices.
__global__ __launch_bounds__(256)
void merge_gather_bn_kernel(const f16* __restrict__ Xs, const float* __restrict__ nrm,
                            const float* __restrict__ pval, const unsigned short* __restrict__ pidx,
                            f16* __restrict__ yf, float* __restrict__ partial) {
    __shared__ float ls[2][4][256];                 // 8 KB (BN reduce)
    __shared__ float Pv[8][TOPK][32];               // 5 KB
    __shared__ unsigned short Pi[8][TOPK][32];      // 2.5 KB
    __shared__ int Fi[32][TOPK];                    // 0.64 KB
    const int tid = threadIdx.x;
    const int row0 = blockIdx.x * 32;

    // ---- phase 1: per-part top5 (parts 0..6: 6 tiles, part 7: 7 tiles)
    {
        const int part = tid >> 5, cl = tid & 31;
        const int col = row0 + cl;
        const int r0 = part * 6;
        const int r1 = (part == 7) ? NTILE : (r0 + 6);
        float bv5[TOPK]; int bi5[TOPK];
#pragma unroll
        for (int s = 0; s < TOPK; ++s) { bv5[s] = -FLT_MAX; bi5[s] = 0; }
        for (int r = r0; r < r1; ++r) {
#pragma unroll
            for (int s = 0; s < TOPK; ++s) {
                const size_t o = ((size_t)(r * TOPK + s)) * NROWS + col;
                ins5(pval[o], (int)pidx[o], bv5, bi5);
            }
        }
#pragma unroll
        for (int s = 0; s < TOPK; ++s) { Pv[part][s][cl] = bv5[s]; Pi[part][s][cl] = (unsigned short)bi5[s]; }
    }
    __syncthreads();

    // ---- phase 2: final per-column merge (ascending part order = ascending tiles)
    if (tid < 32) {
        float cv[TOPK]; int ci[TOPK];
#pragma unroll
        for (int s = 0; s < TOPK; ++s) { cv[s] = -FLT_MAX; ci[s] = 0; }
#pragma unroll
        for (int pp = 0; pp < 8; ++pp)
#pragma unroll
            for (int s = 0; s < TOPK; ++s) ins5(Pv[pp][s][tid], (int)Pi[pp][s][tid], cv, ci);
#pragma unroll
        for (int s = 0; s < TOPK; ++s) Fi[tid][s] = ci[s];
    }
    __syncthreads();

    // ---- phase 3: gather (normalized f16 pair * nrm) + max + BN partials
    const int wid = tid >> 6, lane = tid & 63;
    const int lrow0 = wid * 8;
    float s1x = 0, s1y = 0, s1z = 0, s1w = 0;
    float s2x = 0, s2y = 0, s2z = 0, s2w = 0;
    for (int rr = 0; rr < 8; ++rr) {
        const int lrow = lrow0 + rr;
        const int row = row0 + lrow;
        const int b = row / THW;
        const f16* base = Xs + (size_t)b * THW * 512;
        const float* nb = nrm + (size_t)b * THW;
        float4 m = make_float4(-FLT_MAX, -FLT_MAX, -FLT_MAX, -FLT_MAX);
#pragma unroll
        for (int i = 0; i < TOPK; ++i) {
            const int t = Fi[lrow][i];
            const float nv = nb[t];
            const f16* rp = base + (size_t)t * 512 + lane * 4;
            const half4 h = *(const half4*)rp;
            const half4 l = *(const half4*)(rp + 256);
            m.x = fmaxf(m.x, ((float)h.x + (float)l.x) * nv);
            m.y = fmaxf(m.y, ((float)h.y + (float)l.y) * nv);
            m.z = fmaxf(m.z, ((float)h.z + (float)l.z) * nv);
            m.w = fmaxf(m.w, ((float)h.w + (float)l.w) * nv);
        }
        half4 ym; ym.x = (f16)m.x; ym.y = (f16)m.y; ym.z = (f16)m.z; ym.w = (f16)m.w;
        *(half4*)(yf + (size_t)row * CCH + lane * 4) = ym;
        s1x += m.x; s1y += m.y; s1z += m.z; s1w += m.w;
        s2x += m.x * m.x; s2y += m.y * m.y; s2z += m.z * m.z; s2w += m.w * m.w;
    }
    *(float4*)&ls[0][wid][lane * 4] = make_float4(s1x, s1y, s1z, s1w);
    *(float4*)&ls[1][wid][lane * 4] = make_float4(s2x, s2y, s2z, s2w);
    __syncthreads();
    const float a  = ls[0][0][tid] + ls[0][1][tid] + ls[0][2][tid] + ls[0][3][tid];
    const float b2 = ls[1][0][tid] + ls[1][1][tid] + ls[1][2][tid] + ls[1][3][tid];
    partial[(size_t)blockIdx.x * 512 + tid] = a;
    partial[(size_t)blockIdx.x * 512 + 256 + tid] = b2;
}

// ------------------------------------------------- 5. BN finalize -> scale/shift
__global__ __launch_bounds__(256)
void bn_final_kernel(const float* __restrict__ partial, const float* __restrict__ gamma,
                     const float* __restrict__ beta, float* __restrict__ ab) {
    const int c = blockIdx.x;
    const int tid = threadIdx.x;
    float s1 = 0, s2 = 0;
    for (int p = tid; p < 784; p += 256) {
        s1 += partial[(size_t)p * 512 + c];
        s2 += partial[(size_t)p * 512 + 256 + c];
    }
    __shared__ float r1[256], r2[256];
    r1[tid] = s1; r2[tid] = s2;
    __syncthreads();
    for (int off = 128; off > 0; off >>= 1) {
        if (tid < off) { r1[tid] += r1[tid + off]; r2[tid] += r2[tid + off]; }
        __syncthreads();
    }
    if (tid == 0) {
        const float inv_n = 1.0f / 25088.0f;
        const float mean = r1[0] * inv_n;
        const float var  = r2[0] * inv_n - mean * mean;
        const float a = gamma[c] / sqrtf(var + 1e-5f);
        ab[c] = a;
        ab[256 + c] = beta[c] - mean * a;
    }
}

// ------------------------------------------------- 6. relu(BN) -> 1x1 conv (f16 MFMA) + identity
// Epilogue vectorized: per (i,q) the 4 reg outputs are 4 consecutive hw
// (784-boundary cannot fall inside: Rb%4==0, 784%4==0) -> float4 x-load/out-store.
__global__ __launch_bounds__(256, 2)
void conv_f16_kernel(const f16* __restrict__ yf, const float* __restrict__ w,
                     const float* __restrict__ ab, const float* __restrict__ cb,
                     const float* __restrict__ x, float* __restrict__ out) {
    __shared__ __align__(16) f16 smem[2 * 128 * 64];
    f16* As = smem;
    f16* Ws = smem + 8192;

    const int tid = threadIdx.x;
    const int lane = tid & 63, wid = tid >> 6;
    const int wr = (wid >> 1) * 64, wc = (wid & 1) * 64;
    const int lm = lane & 15, q = lane >> 4;
    const int lm7 = lm & 7;
    const int R0 = blockIdx.x * 128;
    const int o0 = blockIdx.y * 128;
    const int g8 = (tid & 7) * 8;
    const int sr = tid >> 3;

    f32x4 acc[4][4];
#pragma unroll
    for (int i = 0; i < 4; ++i)
#pragma unroll
        for (int j = 0; j < 4; ++j) acc[i][j] = (f32x4)0.0f;

    float cbv[4];
#pragma unroll
    for (int j = 0; j < 4; ++j) cbv[j] = cb[o0 + wc + 16 * j + lm];

    for (int kc = 0; kc < CCH; kc += 64) {
        const int cbase = kc + g8;
        const float4 sa0 = *(const float4*)(ab + cbase);
        const float4 sa1 = *(const float4*)(ab + cbase + 4);
        const float4 sb0 = *(const float4*)(ab + 256 + cbase);
        const float4 sb1 = *(const float4*)(ab + 256 + cbase + 4);
#pragma unroll
        for (int p = 0; p < 4; ++p) {
            const int r = sr + 32 * p;
            const half8 hv = *(const half8*)(yf + (size_t)(R0 + r) * CCH + cbase);
            half8 z;
            z[0] = (f16)fmaxf(fmaf((float)hv[0], sa0.x, sb0.x), 0.0f);
            z[1] = (f16)fmaxf(fmaf((float)hv[1], sa0.y, sb0.y), 0.0f);
            z[2] = (f16)fmaxf(fmaf((float)hv[2], sa0.z, sb0.z), 0.0f);
            z[3] = (f16)fmaxf(fmaf((float)hv[3], sa0.w, sb0.w), 0.0f);
            z[4] = (f16)fmaxf(fmaf((float)hv[4], sa1.x, sb1.x), 0.0f);
            z[5] = (f16)fmaxf(fmaf((float)hv[5], sa1.y, sb1.y), 0.0f);
            z[6] = (f16)fmaxf(fmaf((float)hv[6], sa1.z, sb1.z), 0.0f);
            z[7] = (f16)fmaxf(fmaf((float)hv[7], sa1.w, sb1.w), 0.0f);
            *(half8*)(As + r * 64 + (((tid & 7) ^ (r & 7)) * 8)) = z;
        }
#pragma unroll
        for (int p = 0; p < 4; ++p) {
            const int ol = sr + 32 * p;
            const float4 w0 = *(const float4*)(w + (size_t)(o0 + ol) * CCH + cbase);
            const float4 w1 = *(const float4*)(w + (size_t)(o0 + ol) * CCH + cbase + 4);
            half8 z;
            z[0] = (f16)w0.x; z[1] = (f16)w0.y; z[2] = (f16)w0.z; z[3] = (f16)w0.w;
            z[4] = (f16)w1.x; z[5] = (f16)w1.y; z[6] = (f16)w1.z; z[7] = (f16)w1.w;
            *(half8*)(Ws + ol * 64 + (((tid & 7) ^ (ol & 7)) * 8)) = z;
        }
        __syncthreads();
#pragma unroll
        for (int ks = 0; ks < 2; ++ks) {
            const int ku = (((4 * ks + q) ^ lm7) * 8);
            half8 av[4], bv[4];
#pragma unroll
            for (int i = 0; i < 4; ++i)
                av[i] = *(const half8*)(As + (wr + 16 * i + lm) * 64 + ku);
#pragma unroll
            for (int j = 0; j < 4; ++j)
                bv[j] = *(const half8*)(Ws + (wc + 16 * j + lm) * 64 + ku);
#pragma unroll
            for (int i = 0; i < 4; ++i)
#pragma unroll
                for (int j = 0; j < 4; ++j)
                    acc[i][j] = __builtin_amdgcn_mfma_f32_16x16x32_f16(av[i], bv[j], acc[i][j], 0, 0, 0);
        }
        __syncthreads();
    }
#pragma unroll
    for (int i = 0; i < 4; ++i) {
        const int Rb = R0 + wr + 16 * i + 4 * q;      // 4 consecutive R, same frame
        const int bs = Rb / HW;
        const int hw = Rb - bs * HW;                  // hw % 4 == 0 -> 16B aligned
#pragma unroll
        for (int j = 0; j < 4; ++j) {
            const int o = o0 + wc + 16 * j + lm;
            const size_t oi = ((size_t)bs * CCH + o) * HW + hw;
            const float4 xv = *(const float4*)(x + oi);
            float4 ov;
            ov.x = acc[i][j][0] + cbv[j] + xv.x;
            ov.y = acc[i][j][1] + cbv[j] + xv.y;
            ov.z = acc[i][j][2] + cbv[j] + xv.z;
            ov.w = acc[i][j][3] + cbv[j] + xv.w;
            *(float4*)(out + oi) = ov;
        }
    }
}

// ------------------------------------------------- launch
extern "C" void kernel_launch(void* const* d_in, const int* in_sizes, int n_in,
                              void* d_out, int out_size, void* d_ws, size_t ws_size,
                              hipStream_t stream) {
    const float* x      = (const float*)d_in[0];
    const float* gamma  = (const float*)d_in[1];
    const float* beta   = (const float*)d_in[2];
    const float* conv_w = (const float*)d_in[3];
    const float* conv_b = (const float*)d_in[4];
    float* out = (float*)d_out;

    float* ws = (float*)d_ws;
    f16*   Xsp  = (f16*)ws;                            // [25088][512] halves = 6,422,528 f
    f16*   yf   = (f16*)(ws + 6422528);                // [25088][256] halves = 3,211,264 f
    float* nrm  = ws + 9633792;                        // 25,088
    float* part = ws + 9658880;                        // 401,408
    float* ab   = ws + 10060288;                       // 512
    float* pvalS = ws + 10186240;                              // [49][5][25088] f32 SoA
    unsigned short* pidxS = (unsigned short*)(ws + 16332800);  // [49][5][25088] u16 SoA
    // total = 19,406,080 floats = 77.6 MB

    transpose_norm_split_kernel<<<dim3(32, 25), 256, 0, stream>>>(x, Xsp, nrm);
    gram_sym_kernel<<<dim3(NPAIR, 1, B_), 256, 0, stream>>>(Xsp, pvalS, pidxS);
    merge_gather_bn_kernel<<<NROWS / 32, 256, 0, stream>>>(Xsp, nrm, pvalS, pidxS, yf, part);
    bn_final_kernel<<<256, 256, 0, stream>>>(part, gamma, beta, ab);
    conv_f16_kernel<<<dim3(NROWS / 128, 2), 256, 0, stream>>>(yf, conv_w, ab, conv_b, x, out);
}

// Round 8
// 401.391 us; speedup vs baseline: 1.2233x; 1.0019x over previous
//
#include <hip/hip_runtime.h>
#include <cfloat>
#include <cmath>

#define B_    4
#define SNIP  8
#define CCH   256
#define HW    784
#define THW   6272      // SNIP*HW
#define NROWS 25088     // B_*THW
#define TOPK  5
#define NTILE 49        // 6272/128
#define NPAIR 1225      // 49*50/2

typedef _Float16 f16;
typedef f16   half8 __attribute__((ext_vector_type(8)));
typedef f16   half4 __attribute__((ext_vector_type(4)));
typedef float f32x4 __attribute__((ext_vector_type(4)));

// ---------------------------------------------------------------- utilities
// Branchless sorted-5 insert: 5 v_cmp + cndmask chain, no divergence.
// Strict '>' so ties keep the earlier-inserted entry.
__device__ __forceinline__ void ins5(float key, int idx, float tv[TOPK], int ti[TOPK]) {
    const bool c4 = key > tv[4];
    const bool c3 = key > tv[3];
    const bool c2 = key > tv[2];
    const bool c1 = key > tv[1];
    const bool c0 = key > tv[0];
    tv[4] = c3 ? tv[3] : (c4 ? key : tv[4]);
    ti[4] = c3 ? ti[3] : (c4 ? idx : ti[4]);
    tv[3] = c2 ? tv[2] : (c3 ? key : tv[3]);
    ti[3] = c2 ? ti[2] : (c3 ? idx : ti[3]);
    tv[2] = c1 ? tv[1] : (c2 ? key : tv[2]);
    ti[2] = c1 ? ti[1] : (c2 ? idx : ti[2]);
    tv[1] = c0 ? tv[0] : (c1 ? key : tv[1]);
    ti[1] = c0 ? ti[0] : (c1 ? idx : ti[1]);
    tv[0] = c0 ? key  : tv[0];
    ti[0] = c0 ? idx  : ti[0];
}

__device__ __forceinline__ void async16(const void* g, void* l) {
    __builtin_amdgcn_global_load_lds(
        (const __attribute__((address_space(1))) void*)g,
        (__attribute__((address_space(3))) void*)l, 16, 0, 0);
}

// ------------------------------------------------- 1. fused transpose + rownorm + NORMALIZED f16 split
__global__ __launch_bounds__(256)
void transpose_norm_split_kernel(const float* __restrict__ x, f16* __restrict__ Xs,
                                 float* __restrict__ nrm) {
    __shared__ float T[256][33];
    const int bs = blockIdx.x;
    const int p0 = blockIdx.y * 32;
    const int b = bs >> 3, f = bs & 7;
    const int tid = threadIdx.x;

    const int pl = tid & 31, ch = tid >> 5;
    const int p = p0 + pl;
    if (p < HW) {
#pragma unroll
        for (int cc = 0; cc < 32; ++cc) {
            const int c = cc * 8 + ch;
            T[c][pl] = x[((size_t)bs * CCH + c) * HW + p];
        }
    }
    __syncthreads();

    const int rloc = tid >> 3, k = tid & 7;
    const int gp = p0 + rloc;
    const size_t trow = (size_t)b * THW + (size_t)f * HW + gp;

    float s = 0.0f;
    if (gp < HW) {
#pragma unroll
        for (int j = 0; j < 32; ++j) {
            const float v = T[k * 32 + j][rloc];
            s += v * v;
        }
    }
    s += __shfl_xor(s, 1, 64);
    s += __shfl_xor(s, 2, 64);
    s += __shfl_xor(s, 4, 64);

    if (gp < HW) {
        const float sq = sqrtf(s);
        const float rs = 1.0f / sq;
        if (k == 0) nrm[trow] = sq;
#pragma unroll
        for (int q = 0; q < 4; ++q) {
            half8 hv, lv;
#pragma unroll
            for (int j = 0; j < 8; ++j) {
                const float v = T[k * 32 + q * 8 + j][rloc] * rs;
                const f16 h = (f16)v;
                hv[j] = h;
                lv[j] = (f16)(v - (float)h);
            }
            *(half8*)(Xs + trow * 512 + k * 32 + q * 8) = hv;
            *(half8*)(Xs + trow * 512 + 256 + k * 32 + q * 8) = lv;
        }
    }
}

// ------------------------------------------------- 2a. block-level top5 merge + SoA partial store
__device__ __forceinline__ void block_merge_store(
    const float (*tv)[TOPK], const int (*ti)[TOPK], char* smem,
    int tid, int wid, int q, int wc, int lm,
    int rslot, size_t gcol0,
    float* __restrict__ pval, unsigned short* __restrict__ pidx) {
    float* Mv = (float*)smem;                              // [40][132] f32 = 21120 B
    unsigned short* Mi = (unsigned short*)(smem + 21120);  // [40][132] u16 = 10560 B
    const int slot = (wid >> 1) * 4 + q;
    __syncthreads();                                       // previous smem use done
#pragma unroll
    for (int j = 0; j < 4; ++j) {
        const int c128 = wc + 16 * j + lm;
#pragma unroll
        for (int s = 0; s < TOPK; ++s) {
            Mv[(slot * TOPK + s) * 132 + c128] = tv[j][s];
            Mi[(slot * TOPK + s) * 132 + c128] = (unsigned short)ti[j][s];
        }
    }
    __syncthreads();
    if (tid < 128) {
        float bv5[TOPK]; int bi5[TOPK];
#pragma unroll
        for (int s = 0; s < TOPK; ++s) { bv5[s] = -FLT_MAX; bi5[s] = 0; }
        for (int s = 0; s < 40; ++s) ins5(Mv[s * 132 + tid], (int)Mi[s * 132 + tid], bv5, bi5);
#pragma unroll
        for (int s = 0; s < TOPK; ++s) {
            const size_t o = ((size_t)(rslot * TOPK + s)) * NROWS + gcol0 + tid;
            pval[o] = bv5[s];
            pidx[o] = (unsigned short)bi5[s];
        }
    }
}

// ------------------------------------------------- 2b. SYMMETRIC gram MFMA + dual top-5
// FROZEN at the r5/r7 structure (byte-identical): 33280 LDS, 2-barrier K-loop,
// range-test frame masks, branchless ins5. 259.8us, VGPR 64, zero spill.
__global__ __launch_bounds__(256, 3)
void gram_sym_kernel(const f16* __restrict__ Xs,
                     float* __restrict__ pval, unsigned short* __restrict__ pidx) {
    __shared__ __align__(16) char smem[33280];   // staging 32KB | TT [128][65] f32 | merge 31.7KB
    f16* As = (f16*)smem;                 // [128][64] halves, unit-swizzled
    f16* Bs = As + 8192;
    float* TT = (float*)smem;             // [128][65] transpose buffer (reused post-loop)

    const int tid = threadIdx.x;
    const int lane = tid & 63, wid = tid >> 6;
    const int wr = (wid >> 1) * 64, wc = (wid & 1) * 64;
    const int lm = lane & 15, q = lane >> 4;
    const int lm7 = lm & 7;
    const int b = blockIdx.z;

    // decode pair p -> (ri <= cj), p = cj*(cj+1)/2 + ri
    const int p = blockIdx.x;
    int cj = (int)((sqrtf(8.0f * (float)p + 1.0f) - 1.0f) * 0.5f);
    while ((cj + 1) * (cj + 2) / 2 <= p) ++cj;
    while (cj * (cj + 1) / 2 > p) --cj;
    const int ri = p - cj * (cj + 1) / 2;
    const int t0 = ri * 128, j0 = cj * 128;

    const size_t bbase = (size_t)b * THW;
    const f16* Xb = Xs + bbase * 512;

    const int srow = tid >> 3;
    const int skk = (((tid & 7) ^ (srow & 7)) * 8);

    // frame base of each of this thread's 4 output columns (normal side)
    int loj[4];
#pragma unroll
    for (int j = 0; j < 4; ++j) loj[j] = ((j0 + wc + 16 * j + lm) / HW) * HW;

    float tv[4][TOPK];
    int   ti[4][TOPK];
#pragma unroll
    for (int j = 0; j < 4; ++j)
#pragma unroll
        for (int s = 0; s < TOPK; ++s) { tv[j][s] = -FLT_MAX; ti[j][s] = 0; }

    const int segA[3] = {0, 256, 0};
    const int segB[3] = {0, 0, 256};

    f32x4 acc[4][4];
#pragma unroll
    for (int i = 0; i < 4; ++i)
#pragma unroll
        for (int j = 0; j < 4; ++j) acc[i][j] = (f32x4)0.0f;

    for (int cc = 0; cc < 12; ++cc) {
        const int seg = cc >> 2, k64 = (cc & 3) * 64;
        const int aoff = segA[seg] + k64 + skk;
        const int boff = segB[seg] + k64 + skk;
#pragma unroll
        for (int pp = 0; pp < 4; ++pp)
            async16(Xb + (size_t)(t0 + srow + 32 * pp) * 512 + aoff,
                    smem + wid * 1024 + pp * 4096);
#pragma unroll
        for (int pp = 0; pp < 4; ++pp)
            async16(Xb + (size_t)(j0 + srow + 32 * pp) * 512 + boff,
                    smem + 16384 + wid * 1024 + pp * 4096);
        __syncthreads();
#pragma unroll
        for (int ks = 0; ks < 2; ++ks) {
            const int ku = (((4 * ks + q) ^ lm7) * 8);
            half8 av[4], bv[4];
#pragma unroll
            for (int i = 0; i < 4; ++i)
                av[i] = *(const half8*)(As + (wr + 16 * i + lm) * 64 + ku);
#pragma unroll
            for (int j = 0; j < 4; ++j)
                bv[j] = *(const half8*)(Bs + (wc + 16 * j + lm) * 64 + ku);
#pragma unroll
            for (int i = 0; i < 4; ++i)
#pragma unroll
                for (int j = 0; j < 4; ++j)
                    acc[i][j] = __builtin_amdgcn_mfma_f32_16x16x32_f16(av[i], bv[j], acc[i][j], 0, 0, 0);
        }
        __syncthreads();
    }

    // ---- normal side: columns in cj-tile, candidates t in ri-tile
#pragma unroll
    for (int i = 0; i < 4; ++i) {
        const int tb = t0 + wr + 16 * i + 4 * q;
#pragma unroll
        for (int reg = 0; reg < 4; ++reg) {
            const int t = tb + reg;
#pragma unroll
            for (int j = 0; j < 4; ++j) {
                // same-frame -> key collapses to -FLT_MAX (never displaces)
                const float key = ((unsigned)(t - loj[j]) < (unsigned)HW)
                                  ? -FLT_MAX : acc[i][j][reg];
                ins5(key, t, tv[j], ti[j]);
            }
        }
    }
    block_merge_store(tv, ti, smem, tid, wid, q, wc, lm,
                      ri, bbase + (size_t)j0, pval, pidx);

    // ---- transposed side: columns in ri-tile, candidates s in cj-tile
    if (ri != cj) {
        int lo2[4];
#pragma unroll
        for (int j = 0; j < 4; ++j) lo2[j] = ((t0 + wc + 16 * j + lm) / HW) * HW;
        float tv2[4][TOPK];
        int   ti2[4][TOPK];
#pragma unroll
        for (int j = 0; j < 4; ++j)
#pragma unroll
            for (int s = 0; s < TOPK; ++s) { tv2[j][s] = -FLT_MAX; ti2[j][s] = 0; }
        const int wrb = wid >> 1;
#pragma unroll
        for (int h = 0; h < 2; ++h) {
            __syncthreads();             // previous smem readers done
            if ((wid & 1) == h) {        // waves holding s-half h write their acc
#pragma unroll
                for (int i = 0; i < 4; ++i)
#pragma unroll
                    for (int j = 0; j < 4; ++j)
#pragma unroll
                        for (int reg = 0; reg < 4; ++reg)
                            TT[(wr + 16 * i + 4 * q + reg) * 65 + 16 * j + lm] = acc[i][j][reg];
            }
            __syncthreads();
#pragma unroll
            for (int ii = 0; ii < 2; ++ii) {
                const int spb = wrb * 32 + 16 * ii + 4 * q;    // s-local within half
                const int sg0 = j0 + 64 * h + spb;             // global candidate col
#pragma unroll
                for (int reg = 0; reg < 4; ++reg) {
                    const int sg = sg0 + reg;
#pragma unroll
                    for (int j = 0; j < 4; ++j) {
                        const float raw = TT[(wc + 16 * j + lm) * 65 + spb + reg];
                        const float key = ((unsigned)(sg - lo2[j]) < (unsigned)HW)
                                          ? -FLT_MAX : raw;
                        ins5(key, sg, tv2[j], ti2[j]);
                    }
                }
            }
        }
        block_merge_store(tv2, ti2, smem, tid, wid, q, wc, lm,
                          cj, bbase + (size_t)t0, pval, pidx);
    }
}

// ------------------------------------------------- 3. FUSED merge(49 tile-partials) + gather + max + BN partials
__global__ __launch_bounds__(256)
void merge_gather_bn_kernel(const f16* __restrict__ Xs, const float* __restrict__ nrm,
                            const float* __restrict__ pval, const unsigned short* __restrict__ pidx,
                            f16* __restrict__ yf, float* __restrict__ partial) {
    __shared__ float ls[2][4][256];                 // 8 KB (BN reduce)
    __shared__ float Pv[8][TOPK][32];               // 5 KB
    __shared__ unsigned short Pi[8][TOPK][32];      // 2.5 KB
    __shared__ int Fi[32][TOPK];                    // 0.64 KB
    const int tid = threadIdx.x;
    const int row0 = blockIdx.x * 32;

    // ---- phase 1: per-part top5 (parts 0..6: 6 tiles, part 7: 7 tiles)
    {
        const int part = tid >> 5, cl = tid & 31;
        const int col = row0 + cl;
        const int r0 = part * 6;
        const int r1 = (part == 7) ? NTILE : (r0 + 6);
        float bv5[TOPK]; int bi5[TOPK];
#pragma unroll
        for (int s = 0; s < TOPK; ++s) { bv5[s] = -FLT_MAX; bi5[s] = 0; }
        for (int r = r0; r < r1; ++r) {
#pragma unroll
            for (int s = 0; s < TOPK; ++s) {
                const size_t o = ((size_t)(r * TOPK + s)) * NROWS + col;
                ins5(pval[o], (int)pidx[o], bv5, bi5);
            }
        }
#pragma unroll
        for (int s = 0; s < TOPK; ++s) { Pv[part][s][cl] = bv5[s]; Pi[part][s][cl] = (unsigned short)bi5[s]; }
    }
    __syncthreads();

    // ---- phase 2: final per-column merge (ascending part order = ascending tiles)
    if (tid < 32) {
        float cv[TOPK]; int ci[TOPK];
#pragma unroll
        for (int s = 0; s < TOPK; ++s) { cv[s] = -FLT_MAX; ci[s] = 0; }
#pragma unroll
        for (int pp = 0; pp < 8; ++pp)
#pragma unroll
            for (int s = 0; s < TOPK; ++s) ins5(Pv[pp][s][tid], (int)Pi[pp][s][tid], cv, ci);
#pragma unroll
        for (int s = 0; s < TOPK; ++s) Fi[tid][s] = ci[s];
    }
    __syncthreads();

    // ---- phase 3: gather (normalized f16 pair * nrm) + max + BN partials
    const int wid = tid >> 6, lane = tid & 63;
    const int lrow0 = wid * 8;
    float s1x = 0, s1y = 0, s1z = 0, s1w = 0;
    float s2x = 0, s2y = 0, s2z = 0, s2w = 0;
    for (int rr = 0; rr < 8; ++rr) {
        const int lrow = lrow0 + rr;
        const int row = row0 + lrow;
        const int b = row / THW;
        const f16* base = Xs + (size_t)b * THW * 512;
        const float* nb = nrm + (size_t)b * THW;
        float4 m = make_float4(-FLT_MAX, -FLT_MAX, -FLT_MAX, -FLT_MAX);
#pragma unroll
        for (int i = 0; i < TOPK; ++i) {
            const int t = Fi[lrow][i];
            const float nv = nb[t];
            const f16* rp = base + (size_t)t * 512 + lane * 4;
            const half4 h = *(const half4*)rp;
            const half4 l = *(const half4*)(rp + 256);
            m.x = fmaxf(m.x, ((float)h.x + (float)l.x) * nv);
            m.y = fmaxf(m.y, ((float)h.y + (float)l.y) * nv);
            m.z = fmaxf(m.z, ((float)h.z + (float)l.z) * nv);
            m.w = fmaxf(m.w, ((float)h.w + (float)l.w) * nv);
        }
        half4 ym; ym.x = (f16)m.x; ym.y = (f16)m.y; ym.z = (f16)m.z; ym.w = (f16)m.w;
        *(half4*)(yf + (size_t)row * CCH + lane * 4) = ym;
        s1x += m.x; s1y += m.y; s1z += m.z; s1w += m.w;
        s2x += m.x * m.x; s2y += m.y * m.y; s2z += m.z * m.z; s2w += m.w * m.w;
    }
    *(float4*)&ls[0][wid][lane * 4] = make_float4(s1x, s1y, s1z, s1w);
    *(float4*)&ls[1][wid][lane * 4] = make_float4(s2x, s2y, s2z, s2w);
    __syncthreads();
    const float a  = ls[0][0][tid] + ls[0][1][tid] + ls[0][2][tid] + ls[0][3][tid];
    const float b2 = ls[1][0][tid] + ls[1][1][tid] + ls[1][2][tid] + ls[1][3][tid];
    partial[(size_t)blockIdx.x * 512 + tid] = a;
    partial[(size_t)blockIdx.x * 512 + 256 + tid] = b2;
}

// ------------------------------------------------- 5. BN finalize -> scale/shift
__global__ __launch_bounds__(256)
void bn_final_kernel(const float* __restrict__ partial, const float* __restrict__ gamma,
                     const float* __restrict__ beta, float* __restrict__ ab) {
    const int c = blockIdx.x;
    const int tid = threadIdx.x;
    float s1 = 0, s2 = 0;
    for (int p = tid; p < 784; p += 256) {
        s1 += partial[(size_t)p * 512 + c];
        s2 += partial[(size_t)p * 512 + 256 + c];
    }
    __shared__ float r1[256], r2[256];
    r1[tid] = s1; r2[tid] = s2;
    __syncthreads();
    for (int off = 128; off > 0; off >>= 1) {
        if (tid < off) { r1[tid] += r1[tid + off]; r2[tid] += r2[tid + off]; }
        __syncthreads();
    }
    if (tid == 0) {
        const float inv_n = 1.0f / 25088.0f;
        const float mean = r1[0] * inv_n;
        const float var  = r2[0] * inv_n - mean * mean;
        const float a = gamma[c] / sqrtf(var + 1e-5f);
        ab[c] = a;
        ab[256 + c] = beta[c] - mean * a;
    }
}

// ------------------------------------------------- 6. relu(BN) -> 1x1 conv (f16 MFMA) + identity
// Retiled 64 rows x 128 outs (grid 392x2 = 784 blocks, was 196x2 = 392):
// doubles block-level parallelism (1.53 -> 3.06 block-waves over 256 CUs),
// halves per-block barrier-serialized work; LDS 32 -> 24 KB. Same MFMA/swizzle
// microstructure; per-wave output 32x64 (acc[2][4]).
__global__ __launch_bounds__(256, 2)
void conv_f16_kernel(const f16* __restrict__ yf, const float* __restrict__ w,
                     const float* __restrict__ ab, const float* __restrict__ cb,
                     const float* __restrict__ x, float* __restrict__ out) {
    __shared__ __align__(16) f16 smem[64 * 64 + 128 * 64];   // As 8KB | Ws 16KB
    f16* As = smem;
    f16* Ws = smem + 4096;

    const int tid = threadIdx.x;
    const int lane = tid & 63, wid = tid >> 6;
    const int wr = (wid >> 1) * 32, wc = (wid & 1) * 64;
    const int lm = lane & 15, q = lane >> 4;
    const int lm7 = lm & 7;
    const int R0 = blockIdx.x * 64;
    const int o0 = blockIdx.y * 128;
    const int g8 = (tid & 7) * 8;
    const int sr = tid >> 3;

    f32x4 acc[2][4];
#pragma unroll
    for (int i = 0; i < 2; ++i)
#pragma unroll
        for (int j = 0; j < 4; ++j) acc[i][j] = (f32x4)0.0f;

    float cbv[4];
#pragma unroll
    for (int j = 0; j < 4; ++j) cbv[j] = cb[o0 + wc + 16 * j + lm];

    for (int kc = 0; kc < CCH; kc += 64) {
        const int cbase = kc + g8;
        const float4 sa0 = *(const float4*)(ab + cbase);
        const float4 sa1 = *(const float4*)(ab + cbase + 4);
        const float4 sb0 = *(const float4*)(ab + 256 + cbase);
        const float4 sb1 = *(const float4*)(ab + 256 + cbase + 4);
#pragma unroll
        for (int p = 0; p < 2; ++p) {
            const int r = sr + 32 * p;
            const half8 hv = *(const half8*)(yf + (size_t)(R0 + r) * CCH + cbase);
            half8 z;
            z[0] = (f16)fmaxf(fmaf((float)hv[0], sa0.x, sb0.x), 0.0f);
            z[1] = (f16)fmaxf(fmaf((float)hv[1], sa0.y, sb0.y), 0.0f);
            z[2] = (f16)fmaxf(fmaf((float)hv[2], sa0.z, sb0.z), 0.0f);
            z[3] = (f16)fmaxf(fmaf((float)hv[3], sa0.w, sb0.w), 0.0f);
            z[4] = (f16)fmaxf(fmaf((float)hv[4], sa1.x, sb1.x), 0.0f);
            z[5] = (f16)fmaxf(fmaf((float)hv[5], sa1.y, sb1.y), 0.0f);
            z[6] = (f16)fmaxf(fmaf((float)hv[6], sa1.z, sb1.z), 0.0f);
            z[7] = (f16)fmaxf(fmaf((float)hv[7], sa1.w, sb1.w), 0.0f);
            *(half8*)(As + r * 64 + (((tid & 7) ^ (r & 7)) * 8)) = z;
        }
#pragma unroll
        for (int p = 0; p < 4; ++p) {
            const int ol = sr + 32 * p;
            const float4 w0 = *(const float4*)(w + (size_t)(o0 + ol) * CCH + cbase);
            const float4 w1 = *(const float4*)(w + (size_t)(o0 + ol) * CCH + cbase + 4);
            half8 z;
            z[0] = (f16)w0.x; z[1] = (f16)w0.y; z[2] = (f16)w0.z; z[3] = (f16)w0.w;
            z[4] = (f16)w1.x; z[5] = (f16)w1.y; z[6] = (f16)w1.z; z[7] = (f16)w1.w;
            *(half8*)(Ws + ol * 64 + (((tid & 7) ^ (ol & 7)) * 8)) = z;
        }
        __syncthreads();
#pragma unroll
        for (int ks = 0; ks < 2; ++ks) {
            const int ku = (((4 * ks + q) ^ lm7) * 8);
            half8 av[2], bv[4];
#pragma unroll
            for (int i = 0; i < 2; ++i)
                av[i] = *(const half8*)(As + (wr + 16 * i + lm) * 64 + ku);
#pragma unroll
            for (int j = 0; j < 4; ++j)
                bv[j] = *(const half8*)(Ws + (wc + 16 * j + lm) * 64 + ku);
#pragma unroll
            for (int i = 0; i < 2; ++i)
#pragma unroll
                for (int j = 0; j < 4; ++j)
                    acc[i][j] = __builtin_amdgcn_mfma_f32_16x16x32_f16(av[i], bv[j], acc[i][j], 0, 0, 0);
        }
        __syncthreads();
    }
#pragma unroll
    for (int i = 0; i < 2; ++i) {
        const int Rb = R0 + wr + 16 * i + 4 * q;      // 4 consecutive R, same frame
        const int bs = Rb / HW;
        const int hw = Rb - bs * HW;                  // hw % 4 == 0 -> 16B aligned
#pragma unroll
        for (int j = 0; j < 4; ++j) {
            const int o = o0 + wc + 16 * j + lm;
            const size_t oi = ((size_t)bs * CCH + o) * HW + hw;
            const float4 xv = *(const float4*)(x + oi);
            float4 ov;
            ov.x = acc[i][j][0] + cbv[j] + xv.x;
            ov.y = acc[i][j][1] + cbv[j] + xv.y;
            ov.z = acc[i][j][2] + cbv[j] + xv.z;
            ov.w = acc[i][j][3] + cbv[j] + xv.w;
            *(float4*)(out + oi) = ov;
        }
    }
}

// ------------------------------------------------- launch
extern "C" void kernel_launch(void* const* d_in, const int* in_sizes, int n_in,
                              void* d_out, int out_size, void* d_ws, size_t ws_size,
                              hipStream_t stream) {
    const float* x      = (const float*)d_in[0];
    const float* gamma  = (const float*)d_in[1];
    const float* beta   = (const float*)d_in[2];
    const float* conv_w = (const float*)d_in[3];
    const float* conv_b = (const float*)d_in[4];
    float* out = (float*)d_out;

    float* ws = (float*)d_ws;
    f16*   Xsp  = (f16*)ws;                            // [25088][512] halves = 6,422,528 f
    f16*   yf   = (f16*)(ws + 6422528);                // [25088][256] halves = 3,211,264 f
    float* nrm  = ws + 9633792;                        // 25,088
    float* part = ws + 9658880;                        // 401,408
    float* ab   = ws + 10060288;                       // 512
    float* pvalS = ws + 10186240;                              // [49][5][25088] f32 SoA
    unsigned short* pidxS = (unsigned short*)(ws + 16332800);  // [49][5][25088] u16 SoA
    // total = 19,406,080 floats = 77.6 MB

    transpose_norm_split_kernel<<<dim3(32, 25), 256, 0, stream>>>(x, Xsp, nrm);
    gram_sym_kernel<<<dim3(NPAIR, 1, B_), 256, 0, stream>>>(Xsp, pvalS, pidxS);
    merge_gather_bn_kernel<<<NROWS / 32, 256, 0, stream>>>(Xsp, nrm, pvalS, pidxS, yf, part);
    bn_final_kernel<<<256, 256, 0, stream>>>(part, gamma, beta, ab);
    conv_f16_kernel<<<dim3(NROWS / 64, 2), 256, 0, stream>>>(yf, conv_w, ab, conv_b, x, out);
}

// Round 9
// 396.202 us; speedup vs baseline: 1.2393x; 1.0131x over previous
//
#include <hip/hip_runtime.h>
#include <cfloat>
#include <cmath>

#define B_    4
#define SNIP  8
#define CCH   256
#define HW    784
#define THW   6272      // SNIP*HW
#define NROWS 25088     // B_*THW
#define TOPK  5
#define NTILE 49        // 6272/128
#define NPAIR 1225      // 49*50/2

typedef _Float16 f16;
typedef f16   half8 __attribute__((ext_vector_type(8)));
typedef f16   half4 __attribute__((ext_vector_type(4)));
typedef float f32x4 __attribute__((ext_vector_type(4)));

// ---------------------------------------------------------------- utilities
// Branchless sorted-5 insert: 5 v_cmp + cndmask chain, no divergence.
// Strict '>' so ties keep the earlier-inserted entry.
__device__ __forceinline__ void ins5(float key, int idx, float tv[TOPK], int ti[TOPK]) {
    const bool c4 = key > tv[4];
    const bool c3 = key > tv[3];
    const bool c2 = key > tv[2];
    const bool c1 = key > tv[1];
    const bool c0 = key > tv[0];
    tv[4] = c3 ? tv[3] : (c4 ? key : tv[4]);
    ti[4] = c3 ? ti[3] : (c4 ? idx : ti[4]);
    tv[3] = c2 ? tv[2] : (c3 ? key : tv[3]);
    ti[3] = c2 ? ti[2] : (c3 ? idx : ti[3]);
    tv[2] = c1 ? tv[1] : (c2 ? key : tv[2]);
    ti[2] = c1 ? ti[1] : (c2 ? idx : ti[2]);
    tv[1] = c0 ? tv[0] : (c1 ? key : tv[1]);
    ti[1] = c0 ? ti[0] : (c1 ? idx : ti[1]);
    tv[0] = c0 ? key  : tv[0];
    ti[0] = c0 ? idx  : ti[0];
}

__device__ __forceinline__ void async16(const void* g, void* l) {
    __builtin_amdgcn_global_load_lds(
        (const __attribute__((address_space(1))) void*)g,
        (__attribute__((address_space(3))) void*)l, 16, 0, 0);
}

// ------------------------------------------------- 1. fused transpose + rownorm + NORMALIZED f16 split
__global__ __launch_bounds__(256)
void transpose_norm_split_kernel(const float* __restrict__ x, f16* __restrict__ Xs,
                                 float* __restrict__ nrm) {
    __shared__ float T[256][33];
    const int bs = blockIdx.x;
    const int p0 = blockIdx.y * 32;
    const int b = bs >> 3, f = bs & 7;
    const int tid = threadIdx.x;

    const int pl = tid & 31, ch = tid >> 5;
    const int p = p0 + pl;
    if (p < HW) {
#pragma unroll
        for (int cc = 0; cc < 32; ++cc) {
            const int c = cc * 8 + ch;
            T[c][pl] = x[((size_t)bs * CCH + c) * HW + p];
        }
    }
    __syncthreads();

    const int rloc = tid >> 3, k = tid & 7;
    const int gp = p0 + rloc;
    const size_t trow = (size_t)b * THW + (size_t)f * HW + gp;

    float s = 0.0f;
    if (gp < HW) {
#pragma unroll
        for (int j = 0; j < 32; ++j) {
            const float v = T[k * 32 + j][rloc];
            s += v * v;
        }
    }
    s += __shfl_xor(s, 1, 64);
    s += __shfl_xor(s, 2, 64);
    s += __shfl_xor(s, 4, 64);

    if (gp < HW) {
        const float sq = sqrtf(s);
        const float rs = 1.0f / sq;
        if (k == 0) nrm[trow] = sq;
#pragma unroll
        for (int q = 0; q < 4; ++q) {
            half8 hv, lv;
#pragma unroll
            for (int j = 0; j < 8; ++j) {
                const float v = T[k * 32 + q * 8 + j][rloc] * rs;
                const f16 h = (f16)v;
                hv[j] = h;
                lv[j] = (f16)(v - (float)h);
            }
            *(half8*)(Xs + trow * 512 + k * 32 + q * 8) = hv;
            *(half8*)(Xs + trow * 512 + 256 + k * 32 + q * 8) = lv;
        }
    }
}

// ------------------------------------------------- 2a. block-level top5 merge + SoA partial store
// Split-merge over ALL 256 threads: rows (slot*5+s) 0..19 = slots 0..3 handled
// by tid<128, rows 20..39 = slots 4..7 by tid>=128; halves written back in place
// (each (column,half) cell touched by exactly ONE thread -> no hazard), then
// tid<128 inserts half1's sorted 5. Tie semantics identical to sequential 40-scan:
// ascending-row processing within halves, strict '>' keeps earlier entries.
__device__ __forceinline__ void block_merge_store(
    const float (*tv)[TOPK], const int (*ti)[TOPK], char* smem,
    int tid, int wid, int q, int wc, int lm,
    int rslot, size_t gcol0,
    float* __restrict__ pval, unsigned short* __restrict__ pidx) {
    float* Mv = (float*)smem;                              // [40][132] f32 = 21120 B
    unsigned short* Mi = (unsigned short*)(smem + 21120);  // [40][132] u16 = 10560 B
    const int slot = (wid >> 1) * 4 + q;
    __syncthreads();                                       // previous smem use done
#pragma unroll
    for (int j = 0; j < 4; ++j) {
        const int c128 = wc + 16 * j + lm;
#pragma unroll
        for (int s = 0; s < TOPK; ++s) {
            Mv[(slot * TOPK + s) * 132 + c128] = tv[j][s];
            Mi[(slot * TOPK + s) * 132 + c128] = (unsigned short)ti[j][s];
        }
    }
    __syncthreads();
    // phase A: each (column, half) thread merges its 20 rows, writes top5 back in place
    const int c128 = tid & 127;
    const int h20 = (tid >> 7) * 20;
    float bv5[TOPK]; int bi5[TOPK];
#pragma unroll
    for (int s = 0; s < TOPK; ++s) { bv5[s] = -FLT_MAX; bi5[s] = 0; }
    for (int s = 0; s < 20; ++s)
        ins5(Mv[(h20 + s) * 132 + c128], (int)Mi[(h20 + s) * 132 + c128], bv5, bi5);
#pragma unroll
    for (int s = 0; s < TOPK; ++s) {
        Mv[(h20 + s) * 132 + c128] = bv5[s];
        Mi[(h20 + s) * 132 + c128] = (unsigned short)bi5[s];
    }
    __syncthreads();
    // phase B: tid<128 (holds half0 top5 in regs) inserts half1's sorted 5, stores
    if (tid < 128) {
#pragma unroll
        for (int s = 0; s < TOPK; ++s)
            ins5(Mv[(20 + s) * 132 + tid], (int)Mi[(20 + s) * 132 + tid], bv5, bi5);
#pragma unroll
        for (int s = 0; s < TOPK; ++s) {
            const size_t o = ((size_t)(rslot * TOPK + s)) * NROWS + gcol0 + tid;
            pval[o] = bv5[s];
            pidx[o] = (unsigned short)bi5[s];
        }
    }
}

// ------------------------------------------------- 2b. SYMMETRIC gram MFMA + dual top-5
// FROZEN r5/r7 structure (33280 LDS, 2-barrier K-loop, range-test frame masks,
// branchless ins5) + dead-diagonal early-exit + 256-thread split-merge.
__global__ __launch_bounds__(256, 3)
void gram_sym_kernel(const f16* __restrict__ Xs,
                     float* __restrict__ pval, unsigned short* __restrict__ pidx) {
    __shared__ __align__(16) char smem[33280];   // staging 32KB | TT [128][65] f32 | merge 31.7KB
    f16* As = (f16*)smem;                 // [128][64] halves, unit-swizzled
    f16* Bs = As + 8192;
    float* TT = (float*)smem;             // [128][65] transpose buffer (reused post-loop)

    const int tid = threadIdx.x;
    const int lane = tid & 63, wid = tid >> 6;
    const int wr = (wid >> 1) * 64, wc = (wid & 1) * 64;
    const int lm = lane & 15, q = lane >> 4;
    const int lm7 = lm & 7;
    const int b = blockIdx.z;

    // decode pair p -> (ri <= cj), p = cj*(cj+1)/2 + ri
    const int p = blockIdx.x;
    int cj = (int)((sqrtf(8.0f * (float)p + 1.0f) - 1.0f) * 0.5f);
    while ((cj + 1) * (cj + 2) / 2 <= p) ++cj;
    while (cj * (cj + 1) / 2 > p) --cj;
    const int ri = p - cj * (cj + 1) / 2;
    const int t0 = ri * 128, j0 = cj * 128;

    const size_t bbase = (size_t)b * THW;

    // dead diagonal: tile entirely inside one frame -> every pair same-frame-
    // masked -> partials are exactly (-FLT_MAX, 0). Write them and exit.
    // (42 of 49 diagonal tiles; output bit-identical to running the block.)
    if (ri == cj && (t0 / HW == (t0 + 127) / HW)) {
        if (tid < 128) {
#pragma unroll
            for (int s = 0; s < TOPK; ++s) {
                const size_t o = ((size_t)(ri * TOPK + s)) * NROWS + bbase + (size_t)j0 + tid;
                pval[o] = -FLT_MAX;
                pidx[o] = 0;
            }
        }
        return;
    }

    const f16* Xb = Xs + bbase * 512;

    const int srow = tid >> 3;
    const int skk = (((tid & 7) ^ (srow & 7)) * 8);

    // frame base of each of this thread's 4 output columns (normal side)
    int loj[4];
#pragma unroll
    for (int j = 0; j < 4; ++j) loj[j] = ((j0 + wc + 16 * j + lm) / HW) * HW;

    float tv[4][TOPK];
    int   ti[4][TOPK];
#pragma unroll
    for (int j = 0; j < 4; ++j)
#pragma unroll
        for (int s = 0; s < TOPK; ++s) { tv[j][s] = -FLT_MAX; ti[j][s] = 0; }

    const int segA[3] = {0, 256, 0};
    const int segB[3] = {0, 0, 256};

    f32x4 acc[4][4];
#pragma unroll
    for (int i = 0; i < 4; ++i)
#pragma unroll
        for (int j = 0; j < 4; ++j) acc[i][j] = (f32x4)0.0f;

    for (int cc = 0; cc < 12; ++cc) {
        const int seg = cc >> 2, k64 = (cc & 3) * 64;
        const int aoff = segA[seg] + k64 + skk;
        const int boff = segB[seg] + k64 + skk;
#pragma unroll
        for (int pp = 0; pp < 4; ++pp)
            async16(Xb + (size_t)(t0 + srow + 32 * pp) * 512 + aoff,
                    smem + wid * 1024 + pp * 4096);
#pragma unroll
        for (int pp = 0; pp < 4; ++pp)
            async16(Xb + (size_t)(j0 + srow + 32 * pp) * 512 + boff,
                    smem + 16384 + wid * 1024 + pp * 4096);
        __syncthreads();
#pragma unroll
        for (int ks = 0; ks < 2; ++ks) {
            const int ku = (((4 * ks + q) ^ lm7) * 8);
            half8 av[4], bv[4];
#pragma unroll
            for (int i = 0; i < 4; ++i)
                av[i] = *(const half8*)(As + (wr + 16 * i + lm) * 64 + ku);
#pragma unroll
            for (int j = 0; j < 4; ++j)
                bv[j] = *(const half8*)(Bs + (wc + 16 * j + lm) * 64 + ku);
#pragma unroll
            for (int i = 0; i < 4; ++i)
#pragma unroll
                for (int j = 0; j < 4; ++j)
                    acc[i][j] = __builtin_amdgcn_mfma_f32_16x16x32_f16(av[i], bv[j], acc[i][j], 0, 0, 0);
        }
        __syncthreads();
    }

    // ---- normal side: columns in cj-tile, candidates t in ri-tile
#pragma unroll
    for (int i = 0; i < 4; ++i) {
        const int tb = t0 + wr + 16 * i + 4 * q;
#pragma unroll
        for (int reg = 0; reg < 4; ++reg) {
            const int t = tb + reg;
#pragma unroll
            for (int j = 0; j < 4; ++j) {
                // same-frame -> key collapses to -FLT_MAX (never displaces)
                const float key = ((unsigned)(t - loj[j]) < (unsigned)HW)
                                  ? -FLT_MAX : acc[i][j][reg];
                ins5(key, t, tv[j], ti[j]);
            }
        }
    }
    block_merge_store(tv, ti, smem, tid, wid, q, wc, lm,
                      ri, bbase + (size_t)j0, pval, pidx);

    // ---- transposed side: columns in ri-tile, candidates s in cj-tile
    if (ri != cj) {
        int lo2[4];
#pragma unroll
        for (int j = 0; j < 4; ++j) lo2[j] = ((t0 + wc + 16 * j + lm) / HW) * HW;
        float tv2[4][TOPK];
        int   ti2[4][TOPK];
#pragma unroll
        for (int j = 0; j < 4; ++j)
#pragma unroll
            for (int s = 0; s < TOPK; ++s) { tv2[j][s] = -FLT_MAX; ti2[j][s] = 0; }
        const int wrb = wid >> 1;
#pragma unroll
        for (int h = 0; h < 2; ++h) {
            __syncthreads();             // previous smem readers done
            if ((wid & 1) == h) {        // waves holding s-half h write their acc
#pragma unroll
                for (int i = 0; i < 4; ++i)
#pragma unroll
                    for (int j = 0; j < 4; ++j)
#pragma unroll
                        for (int reg = 0; reg < 4; ++reg)
                            TT[(wr + 16 * i + 4 * q + reg) * 65 + 16 * j + lm] = acc[i][j][reg];
            }
            __syncthreads();
#pragma unroll
            for (int ii = 0; ii < 2; ++ii) {
                const int spb = wrb * 32 + 16 * ii + 4 * q;    // s-local within half
                const int sg0 = j0 + 64 * h + spb;             // global candidate col
#pragma unroll
                for (int reg = 0; reg < 4; ++reg) {
                    const int sg = sg0 + reg;
#pragma unroll
                    for (int j = 0; j < 4; ++j) {
                        const float raw = TT[(wc + 16 * j + lm) * 65 + spb + reg];
                        const float key = ((unsigned)(sg - lo2[j]) < (unsigned)HW)
                                          ? -FLT_MAX : raw;
                        ins5(key, sg, tv2[j], ti2[j]);
                    }
                }
            }
        }
        block_merge_store(tv2, ti2, smem, tid, wid, q, wc, lm,
                          cj, bbase + (size_t)t0, pval, pidx);
    }
}

// ------------------------------------------------- 3. FUSED merge(49 tile-partials) + gather + max + BN partials
__global__ __launch_bounds__(256)
void merge_gather_bn_kernel(const f16* __restrict__ Xs, const float* __restrict__ nrm,
                            const float* __restrict__ pval, const unsigned short* __restrict__ pidx,
                            f16* __restrict__ yf, float* __restrict__ partial) {
    __shared__ float ls[2][4][256];                 // 8 KB (BN reduce)
    __shared__ float Pv[8][TOPK][32];               // 5 KB
    __shared__ unsigned short Pi[8][TOPK][32];      // 2.5 KB
    __shared__ int Fi[32][TOPK];                    // 0.64 KB
    const int tid = threadIdx.x;
    const int row0 = blockIdx.x * 32;

    // ---- phase 1: per-part top5 (parts 0..6: 6 tiles, part 7: 7 tiles)
    {
        const int part = tid >> 5, cl = tid & 31;
        const int col = row0 + cl;
        const int r0 = part * 6;
        const int r1 = (part == 7) ? NTILE : (r0 + 6);
        float bv5[TOPK]; int bi5[TOPK];
#pragma unroll
        for (int s = 0; s < TOPK; ++s) { bv5[s] = -FLT_MAX; bi5[s] = 0; }
        for (int r = r0; r < r1; ++r) {
#pragma unroll
            for (int s = 0; s < TOPK; ++s) {
                const size_t o = ((size_t)(r * TOPK + s)) * NROWS + col;
                ins5(pval[o], (int)pidx[o], bv5, bi5);
            }
        }
#pragma unroll
        for (int s = 0; s < TOPK; ++s) { Pv[part][s][cl] = bv5[s]; Pi[part][s][cl] = (unsigned short)bi5[s]; }
    }
    __syncthreads();

    // ---- phase 2: final per-column merge (ascending part order = ascending tiles)
    if (tid < 32) {
        float cv[TOPK]; int ci[TOPK];
#pragma unroll
        for (int s = 0; s < TOPK; ++s) { cv[s] = -FLT_MAX; ci[s] = 0; }
#pragma unroll
        for (int pp = 0; pp < 8; ++pp)
#pragma unroll
            for (int s = 0; s < TOPK; ++s) ins5(Pv[pp][s][tid], (int)Pi[pp][s][tid], cv, ci);
#pragma unroll
        for (int s = 0; s < TOPK; ++s) Fi[tid][s] = ci[s];
    }
    __syncthreads();

    // ---- phase 3: gather (normalized f16 pair * nrm) + max + BN partials
    const int wid = tid >> 6, lane = tid & 63;
    const int lrow0 = wid * 8;
    float s1x = 0, s1y = 0, s1z = 0, s1w = 0;
    float s2x = 0, s2y = 0, s2z = 0, s2w = 0;
    for (int rr = 0; rr < 8; ++rr) {
        const int lrow = lrow0 + rr;
        const int row = row0 + lrow;
        const int b = row / THW;
        const f16* base = Xs + (size_t)b * THW * 512;
        const float* nb = nrm + (size_t)b * THW;
        float4 m = make_float4(-FLT_MAX, -FLT_MAX, -FLT_MAX, -FLT_MAX);
#pragma unroll
        for (int i = 0; i < TOPK; ++i) {
            const int t = Fi[lrow][i];
            const float nv = nb[t];
            const f16* rp = base + (size_t)t * 512 + lane * 4;
            const half4 h = *(const half4*)rp;
            const half4 l = *(const half4*)(rp + 256);
            m.x = fmaxf(m.x, ((float)h.x + (float)l.x) * nv);
            m.y = fmaxf(m.y, ((float)h.y + (float)l.y) * nv);
            m.z = fmaxf(m.z, ((float)h.z + (float)l.z) * nv);
            m.w = fmaxf(m.w, ((float)h.w + (float)l.w) * nv);
        }
        half4 ym; ym.x = (f16)m.x; ym.y = (f16)m.y; ym.z = (f16)m.z; ym.w = (f16)m.w;
        *(half4*)(yf + (size_t)row * CCH + lane * 4) = ym;
        s1x += m.x; s1y += m.y; s1z += m.z; s1w += m.w;
        s2x += m.x * m.x; s2y += m.y * m.y; s2z += m.z * m.z; s2w += m.w * m.w;
    }
    *(float4*)&ls[0][wid][lane * 4] = make_float4(s1x, s1y, s1z, s1w);
    *(float4*)&ls[1][wid][lane * 4] = make_float4(s2x, s2y, s2z, s2w);
    __syncthreads();
    const float a  = ls[0][0][tid] + ls[0][1][tid] + ls[0][2][tid] + ls[0][3][tid];
    const float b2 = ls[1][0][tid] + ls[1][1][tid] + ls[1][2][tid] + ls[1][3][tid];
    partial[(size_t)blockIdx.x * 512 + tid] = a;
    partial[(size_t)blockIdx.x * 512 + 256 + tid] = b2;
}

// ------------------------------------------------- 5. BN finalize -> scale/shift
__global__ __launch_bounds__(256)
void bn_final_kernel(const float* __restrict__ partial, const float* __restrict__ gamma,
                     const float* __restrict__ beta, float* __restrict__ ab) {
    const int c = blockIdx.x;
    const int tid = threadIdx.x;
    float s1 = 0, s2 = 0;
    for (int p = tid; p < 784; p += 256) {
        s1 += partial[(size_t)p * 512 + c];
        s2 += partial[(size_t)p * 512 + 256 + c];
    }
    __shared__ float r1[256], r2[256];
    r1[tid] = s1; r2[tid] = s2;
    __syncthreads();
    for (int off = 128; off > 0; off >>= 1) {
        if (tid < off) { r1[tid] += r1[tid + off]; r2[tid] += r2[tid + off]; }
        __syncthreads();
    }
    if (tid == 0) {
        const float inv_n = 1.0f / 25088.0f;
        const float mean = r1[0] * inv_n;
        const float var  = r2[0] * inv_n - mean * mean;
        const float a = gamma[c] / sqrtf(var + 1e-5f);
        ab[c] = a;
        ab[256 + c] = beta[c] - mean * a;
    }
}

// ------------------------------------------------- 6. relu(BN) -> 1x1 conv (f16 MFMA) + identity
__global__ __launch_bounds__(256, 2)
void conv_f16_kernel(const f16* __restrict__ yf, const float* __restrict__ w,
                     const float* __restrict__ ab, const float* __restrict__ cb,
                     const float* __restrict__ x, float* __restrict__ out) {
    __shared__ __align__(16) f16 smem[64 * 64 + 128 * 64];   // As 8KB | Ws 16KB
    f16* As = smem;
    f16* Ws = smem + 4096;

    const int tid = threadIdx.x;
    const int lane = tid & 63, wid = tid >> 6;
    const int wr = (wid >> 1) * 32, wc = (wid & 1) * 64;
    const int lm = lane & 15, q = lane >> 4;
    const int lm7 = lm & 7;
    const int R0 = blockIdx.x * 64;
    const int o0 = blockIdx.y * 128;
    const int g8 = (tid & 7) * 8;
    const int sr = tid >> 3;

    f32x4 acc[2][4];
#pragma unroll
    for (int i = 0; i < 2; ++i)
#pragma unroll
        for (int j = 0; j < 4; ++j) acc[i][j] = (f32x4)0.0f;

    float cbv[4];
#pragma unroll
    for (int j = 0; j < 4; ++j) cbv[j] = cb[o0 + wc + 16 * j + lm];

    for (int kc = 0; kc < CCH; kc += 64) {
        const int cbase = kc + g8;
        const float4 sa0 = *(const float4*)(ab + cbase);
        const float4 sa1 = *(const float4*)(ab + cbase + 4);
        const float4 sb0 = *(const float4*)(ab + 256 + cbase);
        const float4 sb1 = *(const float4*)(ab + 256 + cbase + 4);
#pragma unroll
        for (int p = 0; p < 2; ++p) {
            const int r = sr + 32 * p;
            const half8 hv = *(const half8*)(yf + (size_t)(R0 + r) * CCH + cbase);
            half8 z;
            z[0] = (f16)fmaxf(fmaf((float)hv[0], sa0.x, sb0.x), 0.0f);
            z[1] = (f16)fmaxf(fmaf((float)hv[1], sa0.y, sb0.y), 0.0f);
            z[2] = (f16)fmaxf(fmaf((float)hv[2], sa0.z, sb0.z), 0.0f);
            z[3] = (f16)fmaxf(fmaf((float)hv[3], sa0.w, sb0.w), 0.0f);
            z[4] = (f16)fmaxf(fmaf((float)hv[4], sa1.x, sb1.x), 0.0f);
            z[5] = (f16)fmaxf(fmaf((float)hv[5], sa1.y, sb1.y), 0.0f);
            z[6] = (f16)fmaxf(fmaf((float)hv[6], sa1.z, sb1.z), 0.0f);
            z[7] = (f16)fmaxf(fmaf((float)hv[7], sa1.w, sb1.w), 0.0f);
            *(half8*)(As + r * 64 + (((tid & 7) ^ (r & 7)) * 8)) = z;
        }
#pragma unroll
        for (int p = 0; p < 4; ++p) {
            const int ol = sr + 32 * p;
            const float4 w0 = *(const float4*)(w + (size_t)(o0 + ol) * CCH + cbase);
            const float4 w1 = *(const float4*)(w + (size_t)(o0 + ol) * CCH + cbase + 4);
            half8 z;
            z[0] = (f16)w0.x; z[1] = (f16)w0.y; z[2] = (f16)w0.z; z[3] = (f16)w0.w;
            z[4] = (f16)w1.x; z[5] = (f16)w1.y; z[6] = (f16)w1.z; z[7] = (f16)w1.w;
            *(half8*)(Ws + ol * 64 + (((tid & 7) ^ (ol & 7)) * 8)) = z;
        }
        __syncthreads();
#pragma unroll
        for (int ks = 0; ks < 2; ++ks) {
            const int ku = (((4 * ks + q) ^ lm7) * 8);
            half8 av[2], bv[4];
#pragma unroll
            for (int i = 0; i < 2; ++i)
                av[i] = *(const half8*)(As + (wr + 16 * i + lm) * 64 + ku);
#pragma unroll
            for (int j = 0; j < 4; ++j)
                bv[j] = *(const half8*)(Ws + (wc + 16 * j + lm) * 64 + ku);
#pragma unroll
            for (int i = 0; i < 2; ++i)
#pragma unroll
                for (int j = 0; j < 4; ++j)
                    acc[i][j] = __builtin_amdgcn_mfma_f32_16x16x32_f16(av[i], bv[j], acc[i][j], 0, 0, 0);
        }
        __syncthreads();
    }
#pragma unroll
    for (int i = 0; i < 2; ++i) {
        const int Rb = R0 + wr + 16 * i + 4 * q;      // 4 consecutive R, same frame
        const int bs = Rb / HW;
        const int hw = Rb - bs * HW;                  // hw % 4 == 0 -> 16B aligned
#pragma unroll
        for (int j = 0; j < 4; ++j) {
            const int o = o0 + wc + 16 * j + lm;
            const size_t oi = ((size_t)bs * CCH + o) * HW + hw;
            const float4 xv = *(const float4*)(x + oi);
            float4 ov;
            ov.x = acc[i][j][0] + cbv[j] + xv.x;
            ov.y = acc[i][j][1] + cbv[j] + xv.y;
            ov.z = acc[i][j][2] + cbv[j] + xv.z;
            ov.w = acc[i][j][3] + cbv[j] + xv.w;
            *(float4*)(out + oi) = ov;
        }
    }
}

// ------------------------------------------------- launch
extern "C" void kernel_launch(void* const* d_in, const int* in_sizes, int n_in,
                              void* d_out, int out_size, void* d_ws, size_t ws_size,
                              hipStream_t stream) {
    const float* x      = (const float*)d_in[0];
    const float* gamma  = (const float*)d_in[1];
    const float* beta   = (const float*)d_in[2];
    const float* conv_w = (const float*)d_in[3];
    const float* conv_b = (const float*)d_in[4];
    float* out = (float*)d_out;

    float* ws = (float*)d_ws;
    f16*   Xsp  = (f16*)ws;                            // [25088][512] halves = 6,422,528 f
    f16*   yf   = (f16*)(ws + 6422528);                // [25088][256] halves = 3,211,264 f
    float* nrm  = ws + 9633792;                        // 25,088
    float* part = ws + 9658880;                        // 401,408
    float* ab   = ws + 10060288;                       // 512
    float* pvalS = ws + 10186240;                              // [49][5][25088] f32 SoA
    unsigned short* pidxS = (unsigned short*)(ws + 16332800);  // [49][5][25088] u16 SoA
    // total = 19,406,080 floats = 77.6 MB

    transpose_norm_split_kernel<<<dim3(32, 25), 256, 0, stream>>>(x, Xsp, nrm);
    gram_sym_kernel<<<dim3(NPAIR, 1, B_), 256, 0, stream>>>(Xsp, pvalS, pidxS);
    merge_gather_bn_kernel<<<NROWS / 32, 256, 0, stream>>>(Xsp, nrm, pvalS, pidxS, yf, part);
    bn_final_kernel<<<256, 256, 0, stream>>>(part, gamma, beta, ab);
    conv_f16_kernel<<<dim3(NROWS / 64, 2), 256, 0, stream>>>(yf, conv_w, ab, conv_b, x, out);
}